// Round 1
// baseline (472.901 us; speedup 1.0000x reference)
//
#include <hip/hip_runtime.h>
#include <hip/hip_bf16.h>
#include <math.h>

// ---------------------------------------------------------------------------
// GAT 2-layer forward, MI355X.
// Pipeline per call:
//   CSR build (dst-sorted):  hist -> 2-level scan -> scatter      (graph static, built once per launch)
//   L1: gemm(x,W1)->h1 ; dots(h1,al1,ar1)->el1,er1 ; agg(h1)->h1r (relu)
//   L2: gemm(h1r,W2)->h2 ; dots(h2,al2,ar2)->el2,er2 ; agg(h2)->d_out
// ---------------------------------------------------------------------------

#define NEG_SLOPE 0.2f

static __device__ __forceinline__ float lrelu(float v) {
    return v > 0.f ? v : NEG_SLOPE * v;
}

// ---------------------------- CSR build ------------------------------------

__global__ void hist_kernel(const int* __restrict__ dst, int* __restrict__ cnt, int E) {
    int e = blockIdx.x * blockDim.x + threadIdx.x;
    if (e < E) atomicAdd(&cnt[dst[e]], 1);
}

__global__ void scan_a_kernel(const int* __restrict__ cnt, int* __restrict__ bsum, int N) {
    __shared__ int sdata[256];
    int t = threadIdx.x;
    int i = blockIdx.x * 256 + t;
    sdata[t] = (i < N) ? cnt[i] : 0;
    __syncthreads();
    for (int off = 128; off > 0; off >>= 1) {
        if (t < off) sdata[t] += sdata[t + off];
        __syncthreads();
    }
    if (t == 0) bsum[blockIdx.x] = sdata[0];
}

__global__ void scan_b_kernel(const int* __restrict__ bsum, int* __restrict__ boff, int nch) {
    __shared__ int s[256];
    int t = threadIdx.x;
    int v = (t < nch) ? bsum[t] : 0;
    s[t] = v;
    __syncthreads();
    for (int off = 1; off < 256; off <<= 1) {
        int add = (t >= off) ? s[t - off] : 0;
        __syncthreads();
        s[t] += add;
        __syncthreads();
    }
    boff[t] = s[t] - v;  // exclusive
}

__global__ void scan_c_kernel(const int* __restrict__ cnt, const int* __restrict__ boff,
                              int* __restrict__ row_start, int N) {
    __shared__ int s[256];
    int t = threadIdx.x;
    int i = blockIdx.x * 256 + t;
    int v = (i < N) ? cnt[i] : 0;
    s[t] = v;
    __syncthreads();
    for (int off = 1; off < 256; off <<= 1) {
        int add = (t >= off) ? s[t - off] : 0;
        __syncthreads();
        s[t] += add;
        __syncthreads();
    }
    if (i < N) row_start[i] = s[t] - v + boff[blockIdx.x];
}

__global__ void set_end_kernel(int* __restrict__ row_start, int N, int E) {
    row_start[N] = E;
}

__global__ void scatter_kernel(const int* __restrict__ src, const int* __restrict__ dst,
                               const int* __restrict__ row_start, int* __restrict__ fill,
                               int* __restrict__ srcs, int E) {
    int e = blockIdx.x * blockDim.x + threadIdx.x;
    if (e < E) {
        int d = dst[e];
        int pos = row_start[d] + atomicAdd(&fill[d], 1);
        srcs[pos] = src[e];
    }
}

// ---------------------------- GEMM (fp32, 64x64 tile) ----------------------

__global__ __launch_bounds__(256) void gemm_kernel(const float* __restrict__ X,
                                                   const float* __restrict__ W,
                                                   float* __restrict__ C,
                                                   int N, int K, int M) {
    __shared__ float Xs[64][65];
    __shared__ float Ws[64][64];
    const int tid = threadIdx.x;
    const int n0 = blockIdx.x * 64;
    const int c0 = blockIdx.y * 64;
    const int tr = tid >> 4;   // 0..15
    const int tc = tid & 15;   // 0..15
    float acc[4][4] = {};

    for (int k0 = 0; k0 < K; k0 += 64) {
        // stage X tile [64 rows][64 k]
        #pragma unroll
        for (int i = 0; i < 4; ++i) {
            int f = tid + 256 * i;         // 0..1023 float4 slots
            int row = f >> 4;
            int cf = f & 15;
            float4 v = make_float4(0.f, 0.f, 0.f, 0.f);
            if (n0 + row < N)
                v = *(const float4*)(X + (size_t)(n0 + row) * K + k0 + cf * 4);
            Xs[row][cf * 4 + 0] = v.x;
            Xs[row][cf * 4 + 1] = v.y;
            Xs[row][cf * 4 + 2] = v.z;
            Xs[row][cf * 4 + 3] = v.w;
        }
        // stage W tile [64 k][64 cols]
        #pragma unroll
        for (int i = 0; i < 4; ++i) {
            int f = tid + 256 * i;
            int kr = f >> 4;
            int cf = f & 15;
            float4 v = *(const float4*)(W + (size_t)(k0 + kr) * M + c0 + cf * 4);
            *(float4*)&Ws[kr][cf * 4] = v;
        }
        __syncthreads();
        #pragma unroll
        for (int kk = 0; kk < 64; ++kk) {
            float a0 = Xs[tr * 4 + 0][kk];
            float a1 = Xs[tr * 4 + 1][kk];
            float a2 = Xs[tr * 4 + 2][kk];
            float a3 = Xs[tr * 4 + 3][kk];
            float4 b = *(const float4*)&Ws[kk][tc * 4];
            acc[0][0] += a0 * b.x; acc[0][1] += a0 * b.y; acc[0][2] += a0 * b.z; acc[0][3] += a0 * b.w;
            acc[1][0] += a1 * b.x; acc[1][1] += a1 * b.y; acc[1][2] += a1 * b.z; acc[1][3] += a1 * b.w;
            acc[2][0] += a2 * b.x; acc[2][1] += a2 * b.y; acc[2][2] += a2 * b.z; acc[2][3] += a2 * b.w;
            acc[3][0] += a3 * b.x; acc[3][1] += a3 * b.y; acc[3][2] += a3 * b.z; acc[3][3] += a3 * b.w;
        }
        __syncthreads();
    }
    #pragma unroll
    for (int i = 0; i < 4; ++i) {
        int r = n0 + tr * 4 + i;
        if (r < N) {
            *(float4*)(C + (size_t)r * M + c0 + tc * 4) =
                make_float4(acc[i][0], acc[i][1], acc[i][2], acc[i][3]);
        }
    }
}

// ---------------------------- attention dots -------------------------------

// H=4, D=64: one wave per node; lane covers 4 consecutive of 256 elems (one head each)
__global__ void dots_h4_kernel(const float* __restrict__ hbuf,
                               const float* __restrict__ al, const float* __restrict__ ar,
                               float* __restrict__ el, float* __restrict__ er, int N) {
    int wave = (blockIdx.x * blockDim.x + threadIdx.x) >> 6;
    int lane = threadIdx.x & 63;
    if (wave >= N) return;
    float4 hv = *(const float4*)(hbuf + (size_t)wave * 256 + lane * 4);
    float4 av = *(const float4*)(al + lane * 4);
    float4 rv = *(const float4*)(ar + lane * 4);
    float pel = hv.x * av.x + hv.y * av.y + hv.z * av.z + hv.w * av.w;
    float per = hv.x * rv.x + hv.y * rv.y + hv.z * rv.z + hv.w * rv.w;
    #pragma unroll
    for (int mask = 1; mask < 16; mask <<= 1) {
        pel += __shfl_xor(pel, mask);
        per += __shfl_xor(per, mask);
    }
    if ((lane & 15) == 0) {
        el[(size_t)wave * 4 + (lane >> 4)] = pel;
        er[(size_t)wave * 4 + (lane >> 4)] = per;
    }
}

// H=1, D=128
__global__ void dots_h1_kernel(const float* __restrict__ hbuf,
                               const float* __restrict__ al, const float* __restrict__ ar,
                               float* __restrict__ el, float* __restrict__ er, int N) {
    int wave = (blockIdx.x * blockDim.x + threadIdx.x) >> 6;
    int lane = threadIdx.x & 63;
    if (wave >= N) return;
    float2 hv = *(const float2*)(hbuf + (size_t)wave * 128 + lane * 2);
    float2 av = *(const float2*)(al + lane * 2);
    float2 rv = *(const float2*)(ar + lane * 2);
    float pel = hv.x * av.x + hv.y * av.y;
    float per = hv.x * rv.x + hv.y * rv.y;
    #pragma unroll
    for (int mask = 1; mask < 64; mask <<= 1) {
        pel += __shfl_xor(pel, mask);
        per += __shfl_xor(per, mask);
    }
    if (lane == 0) {
        el[wave] = pel;
        er[wave] = per;
    }
}

// ---------------------------- edge softmax + aggregation -------------------
// One wave per dst node. Online softmax over in-edges (gather el[src]),
// then sequential weighted gather of h[src] rows.

template <int H, int D, bool RELU>
__global__ void agg_kernel(const float* __restrict__ hbuf,
                           const float* __restrict__ el, const float* __restrict__ er,
                           const int* __restrict__ srcs, const int* __restrict__ row_start,
                           const float* __restrict__ bias, float* __restrict__ out, int N) {
    constexpr int HD = H * D;
    constexpr int EPL = HD / 64;  // elems per lane
    int wave = (blockIdx.x * blockDim.x + threadIdx.x) >> 6;
    int lane = threadIdx.x & 63;
    if (wave >= N) return;
    const int n = wave;
    const int rs = row_start[n];
    const int re = row_start[n + 1];
    const int h = (lane * EPL) / D;

    float acc[EPL];
    #pragma unroll
    for (int j = 0; j < EPL; ++j) acc[j] = 0.f;

    if (re > rs) {
        float ern[H], m[H], dsum[H];
        #pragma unroll
        for (int hh = 0; hh < H; ++hh) {
            ern[hh] = er[(size_t)n * H + hh];
            m[hh] = -INFINITY;
            dsum[hh] = 0.f;
        }
        // pass 1: online softmax stats, edges striped across lanes
        for (int base = rs; base < re; base += 64) {
            int idx = base + lane;
            if (idx < re) {
                int s = srcs[idx];
                #pragma unroll
                for (int hh = 0; hh < H; ++hh) {
                    float e = lrelu(el[(size_t)s * H + hh] + ern[hh]);
                    float nm = fmaxf(m[hh], e);
                    dsum[hh] = dsum[hh] * expf(m[hh] - nm) + expf(e - nm);
                    m[hh] = nm;
                }
            }
        }
        // cross-lane merge of (m, d)
        #pragma unroll
        for (int mask = 1; mask < 64; mask <<= 1) {
            #pragma unroll
            for (int hh = 0; hh < H; ++hh) {
                float om = __shfl_xor(m[hh], mask);
                float od = __shfl_xor(dsum[hh], mask);
                float nm = fmaxf(m[hh], om);
                float nd = 0.f;
                if (m[hh] > -INFINITY) nd += dsum[hh] * expf(m[hh] - nm);
                if (om > -INFINITY) nd += od * expf(om - nm);
                m[hh] = nm;
                dsum[hh] = nd;
            }
        }
        const float mh = m[h];
        const float invd = 1.f / dsum[h];
        const float erh = ern[h];
        // pass 2: weighted gather of h[src]
        for (int idx = rs; idx < re; ++idx) {
            int s = srcs[idx];
            float e = lrelu(el[(size_t)s * H + h] + erh);
            float a = expf(e - mh) * invd;
            if constexpr (EPL == 4) {
                float4 v = *(const float4*)(hbuf + (size_t)s * HD + lane * 4);
                acc[0] += a * v.x; acc[1] += a * v.y; acc[2] += a * v.z; acc[3] += a * v.w;
            } else {
                float2 v = *(const float2*)(hbuf + (size_t)s * HD + lane * 2);
                acc[0] += a * v.x; acc[1] += a * v.y;
            }
        }
    }
    #pragma unroll
    for (int j = 0; j < EPL; ++j) {
        float o = acc[j] + bias[lane * EPL + j];
        if (RELU) o = fmaxf(o, 0.f);
        out[(size_t)n * HD + lane * EPL + j] = o;
    }
}

// ---------------------------------------------------------------------------

extern "C" void kernel_launch(void* const* d_in, const int* in_sizes, int n_in,
                              void* d_out, int out_size, void* d_ws, size_t ws_size,
                              hipStream_t stream) {
    const float* x   = (const float*)d_in[0];
    const int*   src = (const int*)d_in[1];
    const int*   dst = (const int*)d_in[2];
    const float* W1  = (const float*)d_in[3];
    const float* al1 = (const float*)d_in[4];
    const float* ar1 = (const float*)d_in[5];
    const float* b1  = (const float*)d_in[6];
    const float* W2  = (const float*)d_in[7];
    const float* al2 = (const float*)d_in[8];
    const float* ar2 = (const float*)d_in[9];
    const float* b2  = (const float*)d_in[10];
    float* out = (float*)d_out;

    const int N = in_sizes[0] / 128;  // 50000
    const int E = in_sizes[1];        // 800000

    // workspace layout (bytes, 16B-aligned chunks)
    char* ws = (char*)d_ws;
    size_t oA    = 0;                          // h1 [N*256] f32, later reused as h2 [N*128]
    size_t oB    = oA + (size_t)N * 256 * 4;   // h1r [N*256] f32
    size_t oEl1  = oB + (size_t)N * 256 * 4;   // [N*4]
    size_t oEr1  = oEl1 + (size_t)N * 4 * 4;
    size_t oEl2  = oEr1 + (size_t)N * 4 * 4;   // [N]
    size_t oEr2  = oEl2 + (size_t)N * 4;
    size_t oCnt  = oEr2 + (size_t)N * 4;
    size_t oFill = oCnt + (size_t)N * 4;
    size_t oRow  = oFill + (size_t)N * 4;      // [N+1] -> round up
    size_t oBsum = oRow + (((size_t)(N + 1) * 4 + 15) & ~(size_t)15);
    size_t oBoff = oBsum + 256 * 4;
    size_t oSrcs = oBoff + 256 * 4;            // [E]

    float* h1  = (float*)(ws + oA);
    float* h1r = (float*)(ws + oB);
    float* h2  = (float*)(ws + oA);  // reuse: h1 dead after agg1
    float* el1 = (float*)(ws + oEl1);
    float* er1 = (float*)(ws + oEr1);
    float* el2 = (float*)(ws + oEl2);
    float* er2 = (float*)(ws + oEr2);
    int* cnt       = (int*)(ws + oCnt);
    int* fill      = (int*)(ws + oFill);
    int* row_start = (int*)(ws + oRow);
    int* bsum      = (int*)(ws + oBsum);
    int* boff      = (int*)(ws + oBoff);
    int* srcs      = (int*)(ws + oSrcs);

    const int nch = (N + 255) / 256;

    // ---- CSR build (by dst) ----
    hipMemsetAsync(cnt, 0, (size_t)N * 4, stream);
    hist_kernel<<<(E + 255) / 256, 256, 0, stream>>>(dst, cnt, E);
    scan_a_kernel<<<nch, 256, 0, stream>>>(cnt, bsum, N);
    scan_b_kernel<<<1, 256, 0, stream>>>(bsum, boff, nch);
    scan_c_kernel<<<nch, 256, 0, stream>>>(cnt, boff, row_start, N);
    set_end_kernel<<<1, 1, 0, stream>>>(row_start, N, E);
    hipMemsetAsync(fill, 0, (size_t)N * 4, stream);
    scatter_kernel<<<(E + 255) / 256, 256, 0, stream>>>(src, dst, row_start, fill, srcs, E);

    const int ngemmx = (N + 63) / 64;
    const int nwaveb = (N + 3) / 4;  // 4 waves (nodes) per 256-thread block

    // ---- layer 1 ----
    gemm_kernel<<<dim3(ngemmx, 4), 256, 0, stream>>>(x, W1, h1, N, 128, 256);
    dots_h4_kernel<<<nwaveb, 256, 0, stream>>>(h1, al1, ar1, el1, er1, N);
    agg_kernel<4, 64, true><<<nwaveb, 256, 0, stream>>>(h1, el1, er1, srcs, row_start, b1, h1r, N);

    // ---- layer 2 ----
    gemm_kernel<<<dim3(ngemmx, 2), 256, 0, stream>>>(h1r, W2, h2, N, 256, 128);
    dots_h1_kernel<<<nwaveb, 256, 0, stream>>>(h2, al2, ar2, el2, er2, N);
    agg_kernel<1, 128, false><<<nwaveb, 256, 0, stream>>>(h2, el2, er2, srcs, row_start, b2, out, N);
}

// Round 2
// 451.468 us; speedup vs baseline: 1.0475x; 1.0475x over previous
//
#include <hip/hip_runtime.h>
#include <hip/hip_bf16.h>
#include <math.h>

// ---------------------------------------------------------------------------
// GAT 2-layer forward, MI355X.
//   CSR build (dst-sorted):  hist -> 2-level scan -> scatter
//   L1: gemm(x,W1)->h1 ; dots(h1)->el1,er1 ; agg(h1)->h1r (relu)
//   L2: gemm(h1r,W2)->h2 ; dots(h2)->el2,er2 ; agg(h2)->d_out
// R1->R2: agg softmax de-exp'd: pass1 = fmax-only max reduce (reference's
// two-pass form), pass2 = one __expf/edge accumulating unnormalized sum +
// denom, normalize at end. Was 8 precise expf/edge + 48/merge -> VALU-bound
// 155us/dispatch (VALUBusy 88%).
// ---------------------------------------------------------------------------

#define NEG_SLOPE 0.2f

static __device__ __forceinline__ float lrelu(float v) {
    return v > 0.f ? v : NEG_SLOPE * v;
}

// ---------------------------- CSR build ------------------------------------

__global__ void hist_kernel(const int* __restrict__ dst, int* __restrict__ cnt, int E) {
    int e = blockIdx.x * blockDim.x + threadIdx.x;
    if (e < E) atomicAdd(&cnt[dst[e]], 1);
}

__global__ void scan_a_kernel(const int* __restrict__ cnt, int* __restrict__ bsum, int N) {
    __shared__ int sdata[256];
    int t = threadIdx.x;
    int i = blockIdx.x * 256 + t;
    sdata[t] = (i < N) ? cnt[i] : 0;
    __syncthreads();
    for (int off = 128; off > 0; off >>= 1) {
        if (t < off) sdata[t] += sdata[t + off];
        __syncthreads();
    }
    if (t == 0) bsum[blockIdx.x] = sdata[0];
}

__global__ void scan_b_kernel(const int* __restrict__ bsum, int* __restrict__ boff, int nch) {
    __shared__ int s[256];
    int t = threadIdx.x;
    int v = (t < nch) ? bsum[t] : 0;
    s[t] = v;
    __syncthreads();
    for (int off = 1; off < 256; off <<= 1) {
        int add = (t >= off) ? s[t - off] : 0;
        __syncthreads();
        s[t] += add;
        __syncthreads();
    }
    boff[t] = s[t] - v;  // exclusive
}

__global__ void scan_c_kernel(const int* __restrict__ cnt, const int* __restrict__ boff,
                              int* __restrict__ row_start, int N) {
    __shared__ int s[256];
    int t = threadIdx.x;
    int i = blockIdx.x * 256 + t;
    int v = (i < N) ? cnt[i] : 0;
    s[t] = v;
    __syncthreads();
    for (int off = 1; off < 256; off <<= 1) {
        int add = (t >= off) ? s[t - off] : 0;
        __syncthreads();
        s[t] += add;
        __syncthreads();
    }
    if (i < N) row_start[i] = s[t] - v + boff[blockIdx.x];
}

__global__ void set_end_kernel(int* __restrict__ row_start, int N, int E) {
    row_start[N] = E;
}

__global__ void scatter_kernel(const int* __restrict__ src, const int* __restrict__ dst,
                               const int* __restrict__ row_start, int* __restrict__ fill,
                               int* __restrict__ srcs, int E) {
    int e = blockIdx.x * blockDim.x + threadIdx.x;
    if (e < E) {
        int d = dst[e];
        int pos = row_start[d] + atomicAdd(&fill[d], 1);
        srcs[pos] = src[e];
    }
}

// ---------------------------- GEMM (fp32, 64x64 tile) ----------------------

__global__ __launch_bounds__(256) void gemm_kernel(const float* __restrict__ X,
                                                   const float* __restrict__ W,
                                                   float* __restrict__ C,
                                                   int N, int K, int M) {
    __shared__ float Xs[64][65];
    __shared__ float Ws[64][64];
    const int tid = threadIdx.x;
    const int n0 = blockIdx.x * 64;
    const int c0 = blockIdx.y * 64;
    const int tr = tid >> 4;   // 0..15
    const int tc = tid & 15;   // 0..15
    float acc[4][4] = {};

    for (int k0 = 0; k0 < K; k0 += 64) {
        #pragma unroll
        for (int i = 0; i < 4; ++i) {
            int f = tid + 256 * i;
            int row = f >> 4;
            int cf = f & 15;
            float4 v = make_float4(0.f, 0.f, 0.f, 0.f);
            if (n0 + row < N)
                v = *(const float4*)(X + (size_t)(n0 + row) * K + k0 + cf * 4);
            Xs[row][cf * 4 + 0] = v.x;
            Xs[row][cf * 4 + 1] = v.y;
            Xs[row][cf * 4 + 2] = v.z;
            Xs[row][cf * 4 + 3] = v.w;
        }
        #pragma unroll
        for (int i = 0; i < 4; ++i) {
            int f = tid + 256 * i;
            int kr = f >> 4;
            int cf = f & 15;
            float4 v = *(const float4*)(W + (size_t)(k0 + kr) * M + c0 + cf * 4);
            *(float4*)&Ws[kr][cf * 4] = v;
        }
        __syncthreads();
        #pragma unroll
        for (int kk = 0; kk < 64; ++kk) {
            float a0 = Xs[tr * 4 + 0][kk];
            float a1 = Xs[tr * 4 + 1][kk];
            float a2 = Xs[tr * 4 + 2][kk];
            float a3 = Xs[tr * 4 + 3][kk];
            float4 b = *(const float4*)&Ws[kk][tc * 4];
            acc[0][0] += a0 * b.x; acc[0][1] += a0 * b.y; acc[0][2] += a0 * b.z; acc[0][3] += a0 * b.w;
            acc[1][0] += a1 * b.x; acc[1][1] += a1 * b.y; acc[1][2] += a1 * b.z; acc[1][3] += a1 * b.w;
            acc[2][0] += a2 * b.x; acc[2][1] += a2 * b.y; acc[2][2] += a2 * b.z; acc[2][3] += a2 * b.w;
            acc[3][0] += a3 * b.x; acc[3][1] += a3 * b.y; acc[3][2] += a3 * b.z; acc[3][3] += a3 * b.w;
        }
        __syncthreads();
    }
    #pragma unroll
    for (int i = 0; i < 4; ++i) {
        int r = n0 + tr * 4 + i;
        if (r < N) {
            *(float4*)(C + (size_t)r * M + c0 + tc * 4) =
                make_float4(acc[i][0], acc[i][1], acc[i][2], acc[i][3]);
        }
    }
}

// ---------------------------- attention dots -------------------------------

__global__ void dots_h4_kernel(const float* __restrict__ hbuf,
                               const float* __restrict__ al, const float* __restrict__ ar,
                               float* __restrict__ el, float* __restrict__ er, int N) {
    int wave = (blockIdx.x * blockDim.x + threadIdx.x) >> 6;
    int lane = threadIdx.x & 63;
    if (wave >= N) return;
    float4 hv = *(const float4*)(hbuf + (size_t)wave * 256 + lane * 4);
    float4 av = *(const float4*)(al + lane * 4);
    float4 rv = *(const float4*)(ar + lane * 4);
    float pel = hv.x * av.x + hv.y * av.y + hv.z * av.z + hv.w * av.w;
    float per = hv.x * rv.x + hv.y * rv.y + hv.z * rv.z + hv.w * rv.w;
    #pragma unroll
    for (int mask = 1; mask < 16; mask <<= 1) {
        pel += __shfl_xor(pel, mask);
        per += __shfl_xor(per, mask);
    }
    if ((lane & 15) == 0) {
        el[(size_t)wave * 4 + (lane >> 4)] = pel;
        er[(size_t)wave * 4 + (lane >> 4)] = per;
    }
}

__global__ void dots_h1_kernel(const float* __restrict__ hbuf,
                               const float* __restrict__ al, const float* __restrict__ ar,
                               float* __restrict__ el, float* __restrict__ er, int N) {
    int wave = (blockIdx.x * blockDim.x + threadIdx.x) >> 6;
    int lane = threadIdx.x & 63;
    if (wave >= N) return;
    float2 hv = *(const float2*)(hbuf + (size_t)wave * 128 + lane * 2);
    float2 av = *(const float2*)(al + lane * 2);
    float2 rv = *(const float2*)(ar + lane * 2);
    float pel = hv.x * av.x + hv.y * av.y;
    float per = hv.x * rv.x + hv.y * rv.y;
    #pragma unroll
    for (int mask = 1; mask < 64; mask <<= 1) {
        pel += __shfl_xor(pel, mask);
        per += __shfl_xor(per, mask);
    }
    if (lane == 0) {
        el[wave] = pel;
        er[wave] = per;
    }
}

// ---------------------------- edge softmax + aggregation -------------------
// One wave per dst node. Two-pass (reference-equivalent):
//   pass 1: m[h] = max over in-edges of lrelu(el[src]+er[n])   (fmax only)
//   pass 2: a=__expf(e-m); denom+=a; acc+=a*h[src]; out=acc/denom+bias

template <int H, int D, bool RELU>
__global__ void agg_kernel(const float* __restrict__ hbuf,
                           const float* __restrict__ el, const float* __restrict__ er,
                           const int* __restrict__ srcs, const int* __restrict__ row_start,
                           const float* __restrict__ bias, float* __restrict__ out, int N) {
    constexpr int HD = H * D;
    constexpr int EPL = HD / 64;  // elems per lane
    int wave = (blockIdx.x * blockDim.x + threadIdx.x) >> 6;
    int lane = threadIdx.x & 63;
    if (wave >= N) return;
    const int n = wave;
    const int rs = row_start[n];
    const int re = row_start[n + 1];
    const int h = (lane * EPL) / D;

    float acc[EPL];
    #pragma unroll
    for (int j = 0; j < EPL; ++j) acc[j] = 0.f;

    if (re > rs) {
        float ern[H], m[H];
        #pragma unroll
        for (int hh = 0; hh < H; ++hh) {
            ern[hh] = er[(size_t)n * H + hh];
            m[hh] = -INFINITY;
        }
        // pass 1: max reduce, edges striped across lanes (no exp)
        for (int base = rs; base < re; base += 64) {
            int idx = base + lane;
            if (idx < re) {
                int s = srcs[idx];
                if constexpr (H == 4) {
                    float4 ev = *(const float4*)(el + (size_t)s * 4);
                    m[0] = fmaxf(m[0], lrelu(ev.x + ern[0]));
                    m[1] = fmaxf(m[1], lrelu(ev.y + ern[1]));
                    m[2] = fmaxf(m[2], lrelu(ev.z + ern[2]));
                    m[3] = fmaxf(m[3], lrelu(ev.w + ern[3]));
                } else {
                    m[0] = fmaxf(m[0], lrelu(el[s] + ern[0]));
                }
            }
        }
        // cross-lane max merge (fmax only)
        #pragma unroll
        for (int mask = 1; mask < 64; mask <<= 1) {
            #pragma unroll
            for (int hh = 0; hh < H; ++hh)
                m[hh] = fmaxf(m[hh], __shfl_xor(m[hh], mask));
        }
        const float mh = m[h];
        const float erh = ern[h];
        float denom = 0.f;
        // pass 2: serial weighted gather, unnormalized
        for (int idx = rs; idx < re; ++idx) {
            int s = srcs[idx];
            float e = lrelu(el[(size_t)s * H + h] + erh);
            float a = __expf(e - mh);
            denom += a;
            if constexpr (EPL == 4) {
                float4 v = *(const float4*)(hbuf + (size_t)s * HD + lane * 4);
                acc[0] += a * v.x; acc[1] += a * v.y; acc[2] += a * v.z; acc[3] += a * v.w;
            } else {
                float2 v = *(const float2*)(hbuf + (size_t)s * HD + lane * 2);
                acc[0] += a * v.x; acc[1] += a * v.y;
            }
        }
        const float invd = 1.f / denom;
        #pragma unroll
        for (int j = 0; j < EPL; ++j) acc[j] *= invd;
    }
    #pragma unroll
    for (int j = 0; j < EPL; ++j) {
        float o = acc[j] + bias[lane * EPL + j];
        if (RELU) o = fmaxf(o, 0.f);
        out[(size_t)n * HD + lane * EPL + j] = o;
    }
}

// ---------------------------------------------------------------------------

extern "C" void kernel_launch(void* const* d_in, const int* in_sizes, int n_in,
                              void* d_out, int out_size, void* d_ws, size_t ws_size,
                              hipStream_t stream) {
    const float* x   = (const float*)d_in[0];
    const int*   src = (const int*)d_in[1];
    const int*   dst = (const int*)d_in[2];
    const float* W1  = (const float*)d_in[3];
    const float* al1 = (const float*)d_in[4];
    const float* ar1 = (const float*)d_in[5];
    const float* b1  = (const float*)d_in[6];
    const float* W2  = (const float*)d_in[7];
    const float* al2 = (const float*)d_in[8];
    const float* ar2 = (const float*)d_in[9];
    const float* b2  = (const float*)d_in[10];
    float* out = (float*)d_out;

    const int N = in_sizes[0] / 128;  // 50000
    const int E = in_sizes[1];        // 800000

    char* ws = (char*)d_ws;
    size_t oA    = 0;
    size_t oB    = oA + (size_t)N * 256 * 4;
    size_t oEl1  = oB + (size_t)N * 256 * 4;
    size_t oEr1  = oEl1 + (size_t)N * 4 * 4;
    size_t oEl2  = oEr1 + (size_t)N * 4 * 4;
    size_t oEr2  = oEl2 + (size_t)N * 4;
    size_t oCnt  = oEr2 + (size_t)N * 4;
    size_t oFill = oCnt + (size_t)N * 4;
    size_t oRow  = oFill + (size_t)N * 4;
    size_t oBsum = oRow + (((size_t)(N + 1) * 4 + 15) & ~(size_t)15);
    size_t oBoff = oBsum + 256 * 4;
    size_t oSrcs = oBoff + 256 * 4;

    float* h1  = (float*)(ws + oA);
    float* h1r = (float*)(ws + oB);
    float* h2  = (float*)(ws + oA);  // reuse: h1 dead after agg1
    float* el1 = (float*)(ws + oEl1);
    float* er1 = (float*)(ws + oEr1);
    float* el2 = (float*)(ws + oEl2);
    float* er2 = (float*)(ws + oEr2);
    int* cnt       = (int*)(ws + oCnt);
    int* fill      = (int*)(ws + oFill);
    int* row_start = (int*)(ws + oRow);
    int* bsum      = (int*)(ws + oBsum);
    int* boff      = (int*)(ws + oBoff);
    int* srcs      = (int*)(ws + oSrcs);

    const int nch = (N + 255) / 256;

    // ---- CSR build (by dst) ----
    hipMemsetAsync(cnt, 0, (size_t)N * 4, stream);
    hist_kernel<<<(E + 255) / 256, 256, 0, stream>>>(dst, cnt, E);
    scan_a_kernel<<<nch, 256, 0, stream>>>(cnt, bsum, N);
    scan_b_kernel<<<1, 256, 0, stream>>>(bsum, boff, nch);
    scan_c_kernel<<<nch, 256, 0, stream>>>(cnt, boff, row_start, N);
    set_end_kernel<<<1, 1, 0, stream>>>(row_start, N, E);
    hipMemsetAsync(fill, 0, (size_t)N * 4, stream);
    scatter_kernel<<<(E + 255) / 256, 256, 0, stream>>>(src, dst, row_start, fill, srcs, E);

    const int ngemmx = (N + 63) / 64;
    const int nwaveb = (N + 3) / 4;

    // ---- layer 1 ----
    gemm_kernel<<<dim3(ngemmx, 4), 256, 0, stream>>>(x, W1, h1, N, 128, 256);
    dots_h4_kernel<<<nwaveb, 256, 0, stream>>>(h1, al1, ar1, el1, er1, N);
    agg_kernel<4, 64, true><<<nwaveb, 256, 0, stream>>>(h1, el1, er1, srcs, row_start, b1, h1r, N);

    // ---- layer 2 ----
    gemm_kernel<<<dim3(ngemmx, 2), 256, 0, stream>>>(h1r, W2, h2, N, 256, 128);
    dots_h1_kernel<<<nwaveb, 256, 0, stream>>>(h2, al2, ar2, el2, er2, N);
    agg_kernel<1, 128, false><<<nwaveb, 256, 0, stream>>>(h2, el2, er2, srcs, row_start, b2, out, N);
}

// Round 3
// 408.921 us; speedup vs baseline: 1.1565x; 1.1040x over previous
//
#include <hip/hip_runtime.h>
#include <hip/hip_bf16.h>
#include <math.h>

// ---------------------------------------------------------------------------
// GAT 2-layer forward, MI355X.
//   CSR build (dst-sorted):  hist -> 2-level scan -> scatter
//   L1: gemm(x,W1)->h1 ; dots(h1)->el1,er1 ; agg(h1)->h1r (relu)
//   L2: gemm(h1r,W2)->h2 ; dots(h2)->el2,er2 ; agg(h2)->d_out
// R2->R3: agg pass2 de-latency'd. Edge list + alpha staged in registers
// (striped, one lane per edge), pass2 pulls s_i / a_i via __shfl (register
// only) and issues only independent h[src] row gathers, unrolled x4.
// Was: serial dependent srcs->el->h chain, 130us/dispatch, VALUBusy 29%,
// HBM 45% -> latency-bound.
// ---------------------------------------------------------------------------

#define NEG_SLOPE 0.2f

static __device__ __forceinline__ float lrelu(float v) {
    return v > 0.f ? v : NEG_SLOPE * v;
}

// ---------------------------- CSR build ------------------------------------

__global__ void hist_kernel(const int* __restrict__ dst, int* __restrict__ cnt, int E) {
    int e = blockIdx.x * blockDim.x + threadIdx.x;
    if (e < E) atomicAdd(&cnt[dst[e]], 1);
}

__global__ void scan_a_kernel(const int* __restrict__ cnt, int* __restrict__ bsum, int N) {
    __shared__ int sdata[256];
    int t = threadIdx.x;
    int i = blockIdx.x * 256 + t;
    sdata[t] = (i < N) ? cnt[i] : 0;
    __syncthreads();
    for (int off = 128; off > 0; off >>= 1) {
        if (t < off) sdata[t] += sdata[t + off];
        __syncthreads();
    }
    if (t == 0) bsum[blockIdx.x] = sdata[0];
}

__global__ void scan_b_kernel(const int* __restrict__ bsum, int* __restrict__ boff, int nch) {
    __shared__ int s[256];
    int t = threadIdx.x;
    int v = (t < nch) ? bsum[t] : 0;
    s[t] = v;
    __syncthreads();
    for (int off = 1; off < 256; off <<= 1) {
        int add = (t >= off) ? s[t - off] : 0;
        __syncthreads();
        s[t] += add;
        __syncthreads();
    }
    boff[t] = s[t] - v;  // exclusive
}

__global__ void scan_c_kernel(const int* __restrict__ cnt, const int* __restrict__ boff,
                              int* __restrict__ row_start, int N) {
    __shared__ int s[256];
    int t = threadIdx.x;
    int i = blockIdx.x * 256 + t;
    int v = (i < N) ? cnt[i] : 0;
    s[t] = v;
    __syncthreads();
    for (int off = 1; off < 256; off <<= 1) {
        int add = (t >= off) ? s[t - off] : 0;
        __syncthreads();
        s[t] += add;
        __syncthreads();
    }
    if (i < N) row_start[i] = s[t] - v + boff[blockIdx.x];
}

__global__ void set_end_kernel(int* __restrict__ row_start, int N, int E) {
    row_start[N] = E;
}

__global__ void scatter_kernel(const int* __restrict__ src, const int* __restrict__ dst,
                               const int* __restrict__ row_start, int* __restrict__ fill,
                               int* __restrict__ srcs, int E) {
    int e = blockIdx.x * blockDim.x + threadIdx.x;
    if (e < E) {
        int d = dst[e];
        int pos = row_start[d] + atomicAdd(&fill[d], 1);
        srcs[pos] = src[e];
    }
}

// ---------------------------- GEMM (fp32, 64x64 tile) ----------------------

__global__ __launch_bounds__(256) void gemm_kernel(const float* __restrict__ X,
                                                   const float* __restrict__ W,
                                                   float* __restrict__ C,
                                                   int N, int K, int M) {
    __shared__ float Xs[64][65];
    __shared__ float Ws[64][64];
    const int tid = threadIdx.x;
    const int n0 = blockIdx.x * 64;
    const int c0 = blockIdx.y * 64;
    const int tr = tid >> 4;   // 0..15
    const int tc = tid & 15;   // 0..15
    float acc[4][4] = {};

    for (int k0 = 0; k0 < K; k0 += 64) {
        #pragma unroll
        for (int i = 0; i < 4; ++i) {
            int f = tid + 256 * i;
            int row = f >> 4;
            int cf = f & 15;
            float4 v = make_float4(0.f, 0.f, 0.f, 0.f);
            if (n0 + row < N)
                v = *(const float4*)(X + (size_t)(n0 + row) * K + k0 + cf * 4);
            Xs[row][cf * 4 + 0] = v.x;
            Xs[row][cf * 4 + 1] = v.y;
            Xs[row][cf * 4 + 2] = v.z;
            Xs[row][cf * 4 + 3] = v.w;
        }
        #pragma unroll
        for (int i = 0; i < 4; ++i) {
            int f = tid + 256 * i;
            int kr = f >> 4;
            int cf = f & 15;
            float4 v = *(const float4*)(W + (size_t)(k0 + kr) * M + c0 + cf * 4);
            *(float4*)&Ws[kr][cf * 4] = v;
        }
        __syncthreads();
        #pragma unroll
        for (int kk = 0; kk < 64; ++kk) {
            float a0 = Xs[tr * 4 + 0][kk];
            float a1 = Xs[tr * 4 + 1][kk];
            float a2 = Xs[tr * 4 + 2][kk];
            float a3 = Xs[tr * 4 + 3][kk];
            float4 b = *(const float4*)&Ws[kk][tc * 4];
            acc[0][0] += a0 * b.x; acc[0][1] += a0 * b.y; acc[0][2] += a0 * b.z; acc[0][3] += a0 * b.w;
            acc[1][0] += a1 * b.x; acc[1][1] += a1 * b.y; acc[1][2] += a1 * b.z; acc[1][3] += a1 * b.w;
            acc[2][0] += a2 * b.x; acc[2][1] += a2 * b.y; acc[2][2] += a2 * b.z; acc[2][3] += a2 * b.w;
            acc[3][0] += a3 * b.x; acc[3][1] += a3 * b.y; acc[3][2] += a3 * b.z; acc[3][3] += a3 * b.w;
        }
        __syncthreads();
    }
    #pragma unroll
    for (int i = 0; i < 4; ++i) {
        int r = n0 + tr * 4 + i;
        if (r < N) {
            *(float4*)(C + (size_t)r * M + c0 + tc * 4) =
                make_float4(acc[i][0], acc[i][1], acc[i][2], acc[i][3]);
        }
    }
}

// ---------------------------- attention dots -------------------------------

__global__ void dots_h4_kernel(const float* __restrict__ hbuf,
                               const float* __restrict__ al, const float* __restrict__ ar,
                               float* __restrict__ el, float* __restrict__ er, int N) {
    int wave = (blockIdx.x * blockDim.x + threadIdx.x) >> 6;
    int lane = threadIdx.x & 63;
    if (wave >= N) return;
    float4 hv = *(const float4*)(hbuf + (size_t)wave * 256 + lane * 4);
    float4 av = *(const float4*)(al + lane * 4);
    float4 rv = *(const float4*)(ar + lane * 4);
    float pel = hv.x * av.x + hv.y * av.y + hv.z * av.z + hv.w * av.w;
    float per = hv.x * rv.x + hv.y * rv.y + hv.z * rv.z + hv.w * rv.w;
    #pragma unroll
    for (int mask = 1; mask < 16; mask <<= 1) {
        pel += __shfl_xor(pel, mask);
        per += __shfl_xor(per, mask);
    }
    if ((lane & 15) == 0) {
        el[(size_t)wave * 4 + (lane >> 4)] = pel;
        er[(size_t)wave * 4 + (lane >> 4)] = per;
    }
}

__global__ void dots_h1_kernel(const float* __restrict__ hbuf,
                               const float* __restrict__ al, const float* __restrict__ ar,
                               float* __restrict__ el, float* __restrict__ er, int N) {
    int wave = (blockIdx.x * blockDim.x + threadIdx.x) >> 6;
    int lane = threadIdx.x & 63;
    if (wave >= N) return;
    float2 hv = *(const float2*)(hbuf + (size_t)wave * 128 + lane * 2);
    float2 av = *(const float2*)(al + lane * 2);
    float2 rv = *(const float2*)(ar + lane * 2);
    float pel = hv.x * av.x + hv.y * av.y;
    float per = hv.x * rv.x + hv.y * rv.y;
    #pragma unroll
    for (int mask = 1; mask < 64; mask <<= 1) {
        pel += __shfl_xor(pel, mask);
        per += __shfl_xor(per, mask);
    }
    if (lane == 0) {
        el[wave] = pel;
        er[wave] = per;
    }
}

// ---------------------------- edge softmax + aggregation -------------------
// One wave per dst node. Edge list + alpha staged in registers (striped),
// pass2 pulls s_i / a_i via __shfl and issues only independent row gathers.

template <int H, int D, bool RELU>
__global__ __launch_bounds__(256) void agg_kernel(const float* __restrict__ hbuf,
                           const float* __restrict__ el, const float* __restrict__ er,
                           const int* __restrict__ srcs, const int* __restrict__ row_start,
                           const float* __restrict__ bias, float* __restrict__ out, int N) {
    constexpr int HD = H * D;
    constexpr int EPL = HD / 64;  // elems per lane (4 for L1, 2 for L2)
    int wave = (blockIdx.x * blockDim.x + threadIdx.x) >> 6;
    int lane = threadIdx.x & 63;
    if (wave >= N) return;
    const int n = wave;
    const int rs = row_start[n];
    const int re = row_start[n + 1];
    const int deg = re - rs;

    float acc[EPL];
    #pragma unroll
    for (int j = 0; j < EPL; ++j) acc[j] = 0.f;

    if (deg > 0) {
        const int cnt0 = deg < 64 ? deg : 64;

        if constexpr (H == 4) {
            const int h = lane >> 4;  // 0..3
            const bool hhi = (h >= 2), hodd = (h & 1);
            const float4 ern = *(const float4*)(er + (size_t)n * 4);
            // --- striped stage: lane j owns edge rs+j ---
            int sv = 0;
            float e0 = -INFINITY, e1 = -INFINITY, e2 = -INFINITY, e3 = -INFINITY;
            if (lane < cnt0) {
                sv = srcs[rs + lane];
                float4 ev = *(const float4*)(el + (size_t)sv * 4);
                e0 = lrelu(ev.x + ern.x);
                e1 = lrelu(ev.y + ern.y);
                e2 = lrelu(ev.z + ern.z);
                e3 = lrelu(ev.w + ern.w);
            }
            float m0 = e0, m1 = e1, m2 = e2, m3 = e3;
            for (int base = rs + 64; base < re; base += 64) {  // rare
                int idx = base + lane;
                if (idx < re) {
                    int s = srcs[idx];
                    float4 ev = *(const float4*)(el + (size_t)s * 4);
                    m0 = fmaxf(m0, lrelu(ev.x + ern.x));
                    m1 = fmaxf(m1, lrelu(ev.y + ern.y));
                    m2 = fmaxf(m2, lrelu(ev.z + ern.z));
                    m3 = fmaxf(m3, lrelu(ev.w + ern.w));
                }
            }
            #pragma unroll
            for (int mask = 1; mask < 64; mask <<= 1) {
                m0 = fmaxf(m0, __shfl_xor(m0, mask));
                m1 = fmaxf(m1, __shfl_xor(m1, mask));
                m2 = fmaxf(m2, __shfl_xor(m2, mask));
                m3 = fmaxf(m3, __shfl_xor(m3, mask));
            }
            // unnormalized alphas for this lane's staged edge (0 if invalid)
            float a0 = __expf(e0 - m0), a1 = __expf(e1 - m1);
            float a2 = __expf(e2 - m2), a3 = __expf(e3 - m3);
            float d0 = a0, d1 = a1, d2 = a2, d3 = a3;
            #pragma unroll
            for (int mask = 1; mask < 64; mask <<= 1) {
                d0 += __shfl_xor(d0, mask);
                d1 += __shfl_xor(d1, mask);
                d2 += __shfl_xor(d2, mask);
                d3 += __shfl_xor(d3, mask);
            }
            float dsel  = hhi ? (hodd ? d3 : d2) : (hodd ? d1 : d0);
            const float msel  = hhi ? (hodd ? m3 : m2) : (hodd ? m1 : m0);
            const float ersel = hhi ? (hodd ? ern.w : ern.z) : (hodd ? ern.y : ern.x);
            // --- pass 2: register-resident edges, x4 unrolled gathers ---
            int i = 0;
            for (; i + 4 <= cnt0; i += 4) {
                int s0 = __shfl(sv, i), s1 = __shfl(sv, i + 1);
                int s2 = __shfl(sv, i + 2), s3 = __shfl(sv, i + 3);
                float t00 = __shfl(a0, i), t01 = __shfl(a1, i), t02 = __shfl(a2, i), t03 = __shfl(a3, i);
                float t10 = __shfl(a0, i + 1), t11 = __shfl(a1, i + 1), t12 = __shfl(a2, i + 1), t13 = __shfl(a3, i + 1);
                float t20 = __shfl(a0, i + 2), t21 = __shfl(a1, i + 2), t22 = __shfl(a2, i + 2), t23 = __shfl(a3, i + 2);
                float t30 = __shfl(a0, i + 3), t31 = __shfl(a1, i + 3), t32 = __shfl(a2, i + 3), t33 = __shfl(a3, i + 3);
                float w0 = hhi ? (hodd ? t03 : t02) : (hodd ? t01 : t00);
                float w1 = hhi ? (hodd ? t13 : t12) : (hodd ? t11 : t10);
                float w2 = hhi ? (hodd ? t23 : t22) : (hodd ? t21 : t20);
                float w3 = hhi ? (hodd ? t33 : t32) : (hodd ? t31 : t30);
                float4 v0 = *(const float4*)(hbuf + (size_t)s0 * 256 + lane * 4);
                float4 v1 = *(const float4*)(hbuf + (size_t)s1 * 256 + lane * 4);
                float4 v2 = *(const float4*)(hbuf + (size_t)s2 * 256 + lane * 4);
                float4 v3 = *(const float4*)(hbuf + (size_t)s3 * 256 + lane * 4);
                acc[0] += w0 * v0.x; acc[1] += w0 * v0.y; acc[2] += w0 * v0.z; acc[3] += w0 * v0.w;
                acc[0] += w1 * v1.x; acc[1] += w1 * v1.y; acc[2] += w1 * v1.z; acc[3] += w1 * v1.w;
                acc[0] += w2 * v2.x; acc[1] += w2 * v2.y; acc[2] += w2 * v2.z; acc[3] += w2 * v2.w;
                acc[0] += w3 * v3.x; acc[1] += w3 * v3.y; acc[2] += w3 * v3.z; acc[3] += w3 * v3.w;
            }
            for (; i < cnt0; ++i) {
                int s0 = __shfl(sv, i);
                float t0 = __shfl(a0, i), t1 = __shfl(a1, i), t2 = __shfl(a2, i), t3 = __shfl(a3, i);
                float w = hhi ? (hodd ? t3 : t2) : (hodd ? t1 : t0);
                float4 v = *(const float4*)(hbuf + (size_t)s0 * 256 + lane * 4);
                acc[0] += w * v.x; acc[1] += w * v.y; acc[2] += w * v.z; acc[3] += w * v.w;
            }
            // fallback for deg > 64 (essentially never)
            for (int idx = rs + 64; idx < re; ++idx) {
                int s = srcs[idx];
                float e = lrelu(el[(size_t)s * 4 + h] + ersel);
                float a_ = __expf(e - msel);
                dsel += a_;
                float4 v = *(const float4*)(hbuf + (size_t)s * 256 + lane * 4);
                acc[0] += a_ * v.x; acc[1] += a_ * v.y; acc[2] += a_ * v.z; acc[3] += a_ * v.w;
            }
            float invd = 1.f / dsel;
            #pragma unroll
            for (int j = 0; j < 4; ++j) acc[j] *= invd;
        } else {  // H == 1, D = 128, EPL = 2
            const float ern = er[n];
            int sv = 0;
            float e0 = -INFINITY;
            if (lane < cnt0) {
                sv = srcs[rs + lane];
                e0 = lrelu(el[sv] + ern);
            }
            float m0 = e0;
            for (int base = rs + 64; base < re; base += 64) {  // rare
                int idx = base + lane;
                if (idx < re) m0 = fmaxf(m0, lrelu(el[srcs[idx]] + ern));
            }
            #pragma unroll
            for (int mask = 1; mask < 64; mask <<= 1)
                m0 = fmaxf(m0, __shfl_xor(m0, mask));
            float a0 = __expf(e0 - m0);
            float d0 = a0;
            #pragma unroll
            for (int mask = 1; mask < 64; mask <<= 1)
                d0 += __shfl_xor(d0, mask);
            float dsel = d0;
            int i = 0;
            for (; i + 4 <= cnt0; i += 4) {
                int s0 = __shfl(sv, i), s1 = __shfl(sv, i + 1);
                int s2 = __shfl(sv, i + 2), s3 = __shfl(sv, i + 3);
                float w0 = __shfl(a0, i), w1 = __shfl(a0, i + 1);
                float w2 = __shfl(a0, i + 2), w3 = __shfl(a0, i + 3);
                float2 v0 = *(const float2*)(hbuf + (size_t)s0 * 128 + lane * 2);
                float2 v1 = *(const float2*)(hbuf + (size_t)s1 * 128 + lane * 2);
                float2 v2 = *(const float2*)(hbuf + (size_t)s2 * 128 + lane * 2);
                float2 v3 = *(const float2*)(hbuf + (size_t)s3 * 128 + lane * 2);
                acc[0] += w0 * v0.x; acc[1] += w0 * v0.y;
                acc[0] += w1 * v1.x; acc[1] += w1 * v1.y;
                acc[0] += w2 * v2.x; acc[1] += w2 * v2.y;
                acc[0] += w3 * v3.x; acc[1] += w3 * v3.y;
            }
            for (; i < cnt0; ++i) {
                int s0 = __shfl(sv, i);
                float w = __shfl(a0, i);
                float2 v = *(const float2*)(hbuf + (size_t)s0 * 128 + lane * 2);
                acc[0] += w * v.x; acc[1] += w * v.y;
            }
            for (int idx = rs + 64; idx < re; ++idx) {  // rare
                int s = srcs[idx];
                float e = lrelu(el[s] + ern);
                float a_ = __expf(e - m0);
                dsel += a_;
                float2 v = *(const float2*)(hbuf + (size_t)s * 128 + lane * 2);
                acc[0] += a_ * v.x; acc[1] += a_ * v.y;
            }
            float invd = 1.f / dsel;
            acc[0] *= invd; acc[1] *= invd;
        }
    }
    #pragma unroll
    for (int j = 0; j < EPL; ++j) {
        float o = acc[j] + bias[lane * EPL + j];
        if (RELU) o = fmaxf(o, 0.f);
        out[(size_t)n * HD + lane * EPL + j] = o;
    }
}

// ---------------------------------------------------------------------------

extern "C" void kernel_launch(void* const* d_in, const int* in_sizes, int n_in,
                              void* d_out, int out_size, void* d_ws, size_t ws_size,
                              hipStream_t stream) {
    const float* x   = (const float*)d_in[0];
    const int*   src = (const int*)d_in[1];
    const int*   dst = (const int*)d_in[2];
    const float* W1  = (const float*)d_in[3];
    const float* al1 = (const float*)d_in[4];
    const float* ar1 = (const float*)d_in[5];
    const float* b1  = (const float*)d_in[6];
    const float* W2  = (const float*)d_in[7];
    const float* al2 = (const float*)d_in[8];
    const float* ar2 = (const float*)d_in[9];
    const float* b2  = (const float*)d_in[10];
    float* out = (float*)d_out;

    const int N = in_sizes[0] / 128;  // 50000
    const int E = in_sizes[1];        // 800000

    char* ws = (char*)d_ws;
    size_t oA    = 0;
    size_t oB    = oA + (size_t)N * 256 * 4;
    size_t oEl1  = oB + (size_t)N * 256 * 4;
    size_t oEr1  = oEl1 + (size_t)N * 4 * 4;
    size_t oEl2  = oEr1 + (size_t)N * 4 * 4;
    size_t oEr2  = oEl2 + (size_t)N * 4;
    size_t oCnt  = oEr2 + (size_t)N * 4;
    size_t oFill = oCnt + (size_t)N * 4;
    size_t oRow  = oFill + (size_t)N * 4;
    size_t oBsum = oRow + (((size_t)(N + 1) * 4 + 15) & ~(size_t)15);
    size_t oBoff = oBsum + 256 * 4;
    size_t oSrcs = oBoff + 256 * 4;

    float* h1  = (float*)(ws + oA);
    float* h1r = (float*)(ws + oB);
    float* h2  = (float*)(ws + oA);  // reuse: h1 dead after agg1
    float* el1 = (float*)(ws + oEl1);
    float* er1 = (float*)(ws + oEr1);
    float* el2 = (float*)(ws + oEl2);
    float* er2 = (float*)(ws + oEr2);
    int* cnt       = (int*)(ws + oCnt);
    int* fill      = (int*)(ws + oFill);
    int* row_start = (int*)(ws + oRow);
    int* bsum      = (int*)(ws + oBsum);
    int* boff      = (int*)(ws + oBoff);
    int* srcs      = (int*)(ws + oSrcs);

    const int nch = (N + 255) / 256;

    // ---- CSR build (by dst) ----
    hipMemsetAsync(cnt, 0, (size_t)N * 4, stream);
    hist_kernel<<<(E + 255) / 256, 256, 0, stream>>>(dst, cnt, E);
    scan_a_kernel<<<nch, 256, 0, stream>>>(cnt, bsum, N);
    scan_b_kernel<<<1, 256, 0, stream>>>(bsum, boff, nch);
    scan_c_kernel<<<nch, 256, 0, stream>>>(cnt, boff, row_start, N);
    set_end_kernel<<<1, 1, 0, stream>>>(row_start, N, E);
    hipMemsetAsync(fill, 0, (size_t)N * 4, stream);
    scatter_kernel<<<(E + 255) / 256, 256, 0, stream>>>(src, dst, row_start, fill, srcs, E);

    const int ngemmx = (N + 63) / 64;
    const int nwaveb = (N + 3) / 4;

    // ---- layer 1 ----
    gemm_kernel<<<dim3(ngemmx, 4), 256, 0, stream>>>(x, W1, h1, N, 128, 256);
    dots_h4_kernel<<<nwaveb, 256, 0, stream>>>(h1, al1, ar1, el1, er1, N);
    agg_kernel<4, 64, true><<<nwaveb, 256, 0, stream>>>(h1, el1, er1, srcs, row_start, b1, h1r, N);

    // ---- layer 2 ----
    gemm_kernel<<<dim3(ngemmx, 2), 256, 0, stream>>>(h1r, W2, h2, N, 256, 128);
    dots_h1_kernel<<<nwaveb, 256, 0, stream>>>(h2, al2, ar2, el2, er2, N);
    agg_kernel<1, 128, false><<<nwaveb, 256, 0, stream>>>(h2, el2, er2, srcs, row_start, b2, out, N);
}

// Round 4
// 327.797 us; speedup vs baseline: 1.4427x; 1.2475x over previous
//
#include <hip/hip_runtime.h>
#include <hip/hip_bf16.h>
#include <math.h>

// ---------------------------------------------------------------------------
// GAT 2-layer forward, MI355X.
//   CSR build (dst-sorted):  hist -> 2-level scan -> scatter
//   L1: gemm(x,W1)->h1(bf16) ; dots(h1)->el1,er1 ; agg(h1)->h1r(f32, relu)
//   L2: gemm(h1r,W2)->h2(bf16) ; dots(h2)->el2,er2 ; agg(h2)->d_out(f32)
// R3->R4: h stored as bf16 (GEMM epilogue converts; agg/dots gather bf16,
// accumulate fp32). R3 showed agg is byte-throughput-bound: 6.4 TB/s logical
// gather traffic (= vector-load ceiling), FETCH 402MB @ 3.1 TB/s; unrolling
// didn't help (VALUBusy 29->22%, dur flat). Halve the bytes instead.
// ---------------------------------------------------------------------------

#define NEG_SLOPE 0.2f

static __device__ __forceinline__ float lrelu(float v) {
    return v > 0.f ? v : NEG_SLOPE * v;
}

// bf16 pack/unpack (round-to-nearest-even)
static __device__ __forceinline__ unsigned short f2bf(float f) {
    unsigned int u = __float_as_uint(f);
    u = (u + 0x7fffu + ((u >> 16) & 1u)) >> 16;
    return (unsigned short)u;
}
static __device__ __forceinline__ float bf2f(unsigned int lo16) {
    return __uint_as_float(lo16 << 16);
}

// ---------------------------- CSR build ------------------------------------

__global__ void hist_kernel(const int* __restrict__ dst, int* __restrict__ cnt, int E) {
    int e = blockIdx.x * blockDim.x + threadIdx.x;
    if (e < E) atomicAdd(&cnt[dst[e]], 1);
}

__global__ void scan_a_kernel(const int* __restrict__ cnt, int* __restrict__ bsum, int N) {
    __shared__ int sdata[256];
    int t = threadIdx.x;
    int i = blockIdx.x * 256 + t;
    sdata[t] = (i < N) ? cnt[i] : 0;
    __syncthreads();
    for (int off = 128; off > 0; off >>= 1) {
        if (t < off) sdata[t] += sdata[t + off];
        __syncthreads();
    }
    if (t == 0) bsum[blockIdx.x] = sdata[0];
}

__global__ void scan_b_kernel(const int* __restrict__ bsum, int* __restrict__ boff, int nch) {
    __shared__ int s[256];
    int t = threadIdx.x;
    int v = (t < nch) ? bsum[t] : 0;
    s[t] = v;
    __syncthreads();
    for (int off = 1; off < 256; off <<= 1) {
        int add = (t >= off) ? s[t - off] : 0;
        __syncthreads();
        s[t] += add;
        __syncthreads();
    }
    boff[t] = s[t] - v;  // exclusive
}

__global__ void scan_c_kernel(const int* __restrict__ cnt, const int* __restrict__ boff,
                              int* __restrict__ row_start, int N) {
    __shared__ int s[256];
    int t = threadIdx.x;
    int i = blockIdx.x * 256 + t;
    int v = (i < N) ? cnt[i] : 0;
    s[t] = v;
    __syncthreads();
    for (int off = 1; off < 256; off <<= 1) {
        int add = (t >= off) ? s[t - off] : 0;
        __syncthreads();
        s[t] += add;
        __syncthreads();
    }
    if (i < N) row_start[i] = s[t] - v + boff[blockIdx.x];
}

__global__ void set_end_kernel(int* __restrict__ row_start, int N, int E) {
    row_start[N] = E;
}

__global__ void scatter_kernel(const int* __restrict__ src, const int* __restrict__ dst,
                               const int* __restrict__ row_start, int* __restrict__ fill,
                               int* __restrict__ srcs, int E) {
    int e = blockIdx.x * blockDim.x + threadIdx.x;
    if (e < E) {
        int d = dst[e];
        int pos = row_start[d] + atomicAdd(&fill[d], 1);
        srcs[pos] = src[e];
    }
}

// ---------------------------- GEMM (fp32 in, bf16 out) ---------------------

__global__ __launch_bounds__(256) void gemm_kernel(const float* __restrict__ X,
                                                   const float* __restrict__ W,
                                                   unsigned short* __restrict__ Hb,
                                                   int N, int K, int M) {
    __shared__ float Xs[64][65];
    __shared__ float Ws[64][64];
    const int tid = threadIdx.x;
    const int n0 = blockIdx.x * 64;
    const int c0 = blockIdx.y * 64;
    const int tr = tid >> 4;   // 0..15
    const int tc = tid & 15;   // 0..15
    float acc[4][4] = {};

    for (int k0 = 0; k0 < K; k0 += 64) {
        #pragma unroll
        for (int i = 0; i < 4; ++i) {
            int f = tid + 256 * i;
            int row = f >> 4;
            int cf = f & 15;
            float4 v = make_float4(0.f, 0.f, 0.f, 0.f);
            if (n0 + row < N)
                v = *(const float4*)(X + (size_t)(n0 + row) * K + k0 + cf * 4);
            Xs[row][cf * 4 + 0] = v.x;
            Xs[row][cf * 4 + 1] = v.y;
            Xs[row][cf * 4 + 2] = v.z;
            Xs[row][cf * 4 + 3] = v.w;
        }
        #pragma unroll
        for (int i = 0; i < 4; ++i) {
            int f = tid + 256 * i;
            int kr = f >> 4;
            int cf = f & 15;
            float4 v = *(const float4*)(W + (size_t)(k0 + kr) * M + c0 + cf * 4);
            *(float4*)&Ws[kr][cf * 4] = v;
        }
        __syncthreads();
        #pragma unroll
        for (int kk = 0; kk < 64; ++kk) {
            float a0 = Xs[tr * 4 + 0][kk];
            float a1 = Xs[tr * 4 + 1][kk];
            float a2 = Xs[tr * 4 + 2][kk];
            float a3 = Xs[tr * 4 + 3][kk];
            float4 b = *(const float4*)&Ws[kk][tc * 4];
            acc[0][0] += a0 * b.x; acc[0][1] += a0 * b.y; acc[0][2] += a0 * b.z; acc[0][3] += a0 * b.w;
            acc[1][0] += a1 * b.x; acc[1][1] += a1 * b.y; acc[1][2] += a1 * b.z; acc[1][3] += a1 * b.w;
            acc[2][0] += a2 * b.x; acc[2][1] += a2 * b.y; acc[2][2] += a2 * b.z; acc[2][3] += a2 * b.w;
            acc[3][0] += a3 * b.x; acc[3][1] += a3 * b.y; acc[3][2] += a3 * b.z; acc[3][3] += a3 * b.w;
        }
        __syncthreads();
    }
    #pragma unroll
    for (int i = 0; i < 4; ++i) {
        int r = n0 + tr * 4 + i;
        if (r < N) {
            ushort4 o;
            o.x = f2bf(acc[i][0]); o.y = f2bf(acc[i][1]);
            o.z = f2bf(acc[i][2]); o.w = f2bf(acc[i][3]);
            *(ushort4*)(Hb + (size_t)r * M + c0 + tc * 4) = o;
        }
    }
}

// ---------------------------- attention dots -------------------------------

__global__ void dots_h4_kernel(const unsigned short* __restrict__ hb,
                               const float* __restrict__ al, const float* __restrict__ ar,
                               float* __restrict__ el, float* __restrict__ er, int N) {
    int wave = (blockIdx.x * blockDim.x + threadIdx.x) >> 6;
    int lane = threadIdx.x & 63;
    if (wave >= N) return;
    ushort4 hu = *(const ushort4*)(hb + (size_t)wave * 256 + lane * 4);
    float h0 = bf2f(hu.x), h1 = bf2f(hu.y), h2 = bf2f(hu.z), h3 = bf2f(hu.w);
    float4 av = *(const float4*)(al + lane * 4);
    float4 rv = *(const float4*)(ar + lane * 4);
    float pel = h0 * av.x + h1 * av.y + h2 * av.z + h3 * av.w;
    float per = h0 * rv.x + h1 * rv.y + h2 * rv.z + h3 * rv.w;
    #pragma unroll
    for (int mask = 1; mask < 16; mask <<= 1) {
        pel += __shfl_xor(pel, mask);
        per += __shfl_xor(per, mask);
    }
    if ((lane & 15) == 0) {
        el[(size_t)wave * 4 + (lane >> 4)] = pel;
        er[(size_t)wave * 4 + (lane >> 4)] = per;
    }
}

__global__ void dots_h1_kernel(const unsigned short* __restrict__ hb,
                               const float* __restrict__ al, const float* __restrict__ ar,
                               float* __restrict__ el, float* __restrict__ er, int N) {
    int wave = (blockIdx.x * blockDim.x + threadIdx.x) >> 6;
    int lane = threadIdx.x & 63;
    if (wave >= N) return;
    unsigned int hu = *(const unsigned int*)(hb + (size_t)wave * 128 + lane * 2);
    float h0 = bf2f(hu & 0xffffu), h1 = bf2f(hu >> 16);
    float2 av = *(const float2*)(al + lane * 2);
    float2 rv = *(const float2*)(ar + lane * 2);
    float pel = h0 * av.x + h1 * av.y;
    float per = h0 * rv.x + h1 * rv.y;
    #pragma unroll
    for (int mask = 1; mask < 64; mask <<= 1) {
        pel += __shfl_xor(pel, mask);
        per += __shfl_xor(per, mask);
    }
    if (lane == 0) {
        el[wave] = pel;
        er[wave] = per;
    }
}

// ---------------------------- edge softmax + aggregation -------------------
// One wave per dst node. Edge list + alpha staged in registers (striped),
// pass2 pulls s_i / a_i via __shfl and gathers bf16 h rows, fp32 accumulate.

template <int H, int D, bool RELU>
__global__ __launch_bounds__(256) void agg_kernel(const unsigned short* __restrict__ hb,
                           const float* __restrict__ el, const float* __restrict__ er,
                           const int* __restrict__ srcs, const int* __restrict__ row_start,
                           const float* __restrict__ bias, float* __restrict__ out, int N) {
    constexpr int HD = H * D;
    constexpr int EPL = HD / 64;  // elems per lane (4 for L1, 2 for L2)
    int wave = (blockIdx.x * blockDim.x + threadIdx.x) >> 6;
    int lane = threadIdx.x & 63;
    if (wave >= N) return;
    const int n = wave;
    const int rs = row_start[n];
    const int re = row_start[n + 1];
    const int deg = re - rs;

    float acc[EPL];
    #pragma unroll
    for (int j = 0; j < EPL; ++j) acc[j] = 0.f;

    if (deg > 0) {
        const int cnt0 = deg < 64 ? deg : 64;

        if constexpr (H == 4) {
            const int h = lane >> 4;  // 0..3
            const bool hhi = (h >= 2), hodd = (h & 1);
            const float4 ern = *(const float4*)(er + (size_t)n * 4);
            // --- striped stage: lane j owns edge rs+j ---
            int sv = 0;
            float e0 = -INFINITY, e1 = -INFINITY, e2 = -INFINITY, e3 = -INFINITY;
            if (lane < cnt0) {
                sv = srcs[rs + lane];
                float4 ev = *(const float4*)(el + (size_t)sv * 4);
                e0 = lrelu(ev.x + ern.x);
                e1 = lrelu(ev.y + ern.y);
                e2 = lrelu(ev.z + ern.z);
                e3 = lrelu(ev.w + ern.w);
            }
            float m0 = e0, m1 = e1, m2 = e2, m3 = e3;
            for (int base = rs + 64; base < re; base += 64) {  // rare
                int idx = base + lane;
                if (idx < re) {
                    int s = srcs[idx];
                    float4 ev = *(const float4*)(el + (size_t)s * 4);
                    m0 = fmaxf(m0, lrelu(ev.x + ern.x));
                    m1 = fmaxf(m1, lrelu(ev.y + ern.y));
                    m2 = fmaxf(m2, lrelu(ev.z + ern.z));
                    m3 = fmaxf(m3, lrelu(ev.w + ern.w));
                }
            }
            #pragma unroll
            for (int mask = 1; mask < 64; mask <<= 1) {
                m0 = fmaxf(m0, __shfl_xor(m0, mask));
                m1 = fmaxf(m1, __shfl_xor(m1, mask));
                m2 = fmaxf(m2, __shfl_xor(m2, mask));
                m3 = fmaxf(m3, __shfl_xor(m3, mask));
            }
            float a0 = __expf(e0 - m0), a1 = __expf(e1 - m1);
            float a2 = __expf(e2 - m2), a3 = __expf(e3 - m3);
            float d0 = a0, d1 = a1, d2 = a2, d3 = a3;
            #pragma unroll
            for (int mask = 1; mask < 64; mask <<= 1) {
                d0 += __shfl_xor(d0, mask);
                d1 += __shfl_xor(d1, mask);
                d2 += __shfl_xor(d2, mask);
                d3 += __shfl_xor(d3, mask);
            }
            float dsel  = hhi ? (hodd ? d3 : d2) : (hodd ? d1 : d0);
            const float msel  = hhi ? (hodd ? m3 : m2) : (hodd ? m1 : m0);
            const float ersel = hhi ? (hodd ? ern.w : ern.z) : (hodd ? ern.y : ern.x);
            // --- pass 2: register-resident edges, x4 unrolled bf16 gathers ---
            int i = 0;
            for (; i + 4 <= cnt0; i += 4) {
                int s0 = __shfl(sv, i), s1 = __shfl(sv, i + 1);
                int s2 = __shfl(sv, i + 2), s3 = __shfl(sv, i + 3);
                float t00 = __shfl(a0, i), t01 = __shfl(a1, i), t02 = __shfl(a2, i), t03 = __shfl(a3, i);
                float t10 = __shfl(a0, i + 1), t11 = __shfl(a1, i + 1), t12 = __shfl(a2, i + 1), t13 = __shfl(a3, i + 1);
                float t20 = __shfl(a0, i + 2), t21 = __shfl(a1, i + 2), t22 = __shfl(a2, i + 2), t23 = __shfl(a3, i + 2);
                float t30 = __shfl(a0, i + 3), t31 = __shfl(a1, i + 3), t32 = __shfl(a2, i + 3), t33 = __shfl(a3, i + 3);
                float w0 = hhi ? (hodd ? t03 : t02) : (hodd ? t01 : t00);
                float w1 = hhi ? (hodd ? t13 : t12) : (hodd ? t11 : t10);
                float w2 = hhi ? (hodd ? t23 : t22) : (hodd ? t21 : t20);
                float w3 = hhi ? (hodd ? t33 : t32) : (hodd ? t31 : t30);
                uint2 v0 = *(const uint2*)(hb + (size_t)s0 * 256 + lane * 4);
                uint2 v1 = *(const uint2*)(hb + (size_t)s1 * 256 + lane * 4);
                uint2 v2 = *(const uint2*)(hb + (size_t)s2 * 256 + lane * 4);
                uint2 v3 = *(const uint2*)(hb + (size_t)s3 * 256 + lane * 4);
                acc[0] += w0 * bf2f(v0.x & 0xffffu); acc[1] += w0 * bf2f(v0.x >> 16);
                acc[2] += w0 * bf2f(v0.y & 0xffffu); acc[3] += w0 * bf2f(v0.y >> 16);
                acc[0] += w1 * bf2f(v1.x & 0xffffu); acc[1] += w1 * bf2f(v1.x >> 16);
                acc[2] += w1 * bf2f(v1.y & 0xffffu); acc[3] += w1 * bf2f(v1.y >> 16);
                acc[0] += w2 * bf2f(v2.x & 0xffffu); acc[1] += w2 * bf2f(v2.x >> 16);
                acc[2] += w2 * bf2f(v2.y & 0xffffu); acc[3] += w2 * bf2f(v2.y >> 16);
                acc[0] += w3 * bf2f(v3.x & 0xffffu); acc[1] += w3 * bf2f(v3.x >> 16);
                acc[2] += w3 * bf2f(v3.y & 0xffffu); acc[3] += w3 * bf2f(v3.y >> 16);
            }
            for (; i < cnt0; ++i) {
                int s0 = __shfl(sv, i);
                float t0 = __shfl(a0, i), t1 = __shfl(a1, i), t2 = __shfl(a2, i), t3 = __shfl(a3, i);
                float w = hhi ? (hodd ? t3 : t2) : (hodd ? t1 : t0);
                uint2 v = *(const uint2*)(hb + (size_t)s0 * 256 + lane * 4);
                acc[0] += w * bf2f(v.x & 0xffffu); acc[1] += w * bf2f(v.x >> 16);
                acc[2] += w * bf2f(v.y & 0xffffu); acc[3] += w * bf2f(v.y >> 16);
            }
            for (int idx = rs + 64; idx < re; ++idx) {  // rare
                int s = srcs[idx];
                float e = lrelu(el[(size_t)s * 4 + h] + ersel);
                float a_ = __expf(e - msel);
                dsel += a_;
                uint2 v = *(const uint2*)(hb + (size_t)s * 256 + lane * 4);
                acc[0] += a_ * bf2f(v.x & 0xffffu); acc[1] += a_ * bf2f(v.x >> 16);
                acc[2] += a_ * bf2f(v.y & 0xffffu); acc[3] += a_ * bf2f(v.y >> 16);
            }
            float invd = 1.f / dsel;
            #pragma unroll
            for (int j = 0; j < 4; ++j) acc[j] *= invd;
        } else {  // H == 1, D = 128, EPL = 2
            const float ern = er[n];
            int sv = 0;
            float e0 = -INFINITY;
            if (lane < cnt0) {
                sv = srcs[rs + lane];
                e0 = lrelu(el[sv] + ern);
            }
            float m0 = e0;
            for (int base = rs + 64; base < re; base += 64) {  // rare
                int idx = base + lane;
                if (idx < re) m0 = fmaxf(m0, lrelu(el[srcs[idx]] + ern));
            }
            #pragma unroll
            for (int mask = 1; mask < 64; mask <<= 1)
                m0 = fmaxf(m0, __shfl_xor(m0, mask));
            float a0 = __expf(e0 - m0);
            float d0 = a0;
            #pragma unroll
            for (int mask = 1; mask < 64; mask <<= 1)
                d0 += __shfl_xor(d0, mask);
            float dsel = d0;
            int i = 0;
            for (; i + 4 <= cnt0; i += 4) {
                int s0 = __shfl(sv, i), s1 = __shfl(sv, i + 1);
                int s2 = __shfl(sv, i + 2), s3 = __shfl(sv, i + 3);
                float w0 = __shfl(a0, i), w1 = __shfl(a0, i + 1);
                float w2 = __shfl(a0, i + 2), w3 = __shfl(a0, i + 3);
                unsigned int v0 = *(const unsigned int*)(hb + (size_t)s0 * 128 + lane * 2);
                unsigned int v1 = *(const unsigned int*)(hb + (size_t)s1 * 128 + lane * 2);
                unsigned int v2 = *(const unsigned int*)(hb + (size_t)s2 * 128 + lane * 2);
                unsigned int v3 = *(const unsigned int*)(hb + (size_t)s3 * 128 + lane * 2);
                acc[0] += w0 * bf2f(v0 & 0xffffu); acc[1] += w0 * bf2f(v0 >> 16);
                acc[0] += w1 * bf2f(v1 & 0xffffu); acc[1] += w1 * bf2f(v1 >> 16);
                acc[0] += w2 * bf2f(v2 & 0xffffu); acc[1] += w2 * bf2f(v2 >> 16);
                acc[0] += w3 * bf2f(v3 & 0xffffu); acc[1] += w3 * bf2f(v3 >> 16);
            }
            for (; i < cnt0; ++i) {
                int s0 = __shfl(sv, i);
                float w = __shfl(a0, i);
                unsigned int v = *(const unsigned int*)(hb + (size_t)s0 * 128 + lane * 2);
                acc[0] += w * bf2f(v & 0xffffu); acc[1] += w * bf2f(v >> 16);
            }
            for (int idx = rs + 64; idx < re; ++idx) {  // rare
                int s = srcs[idx];
                float e = lrelu(el[s] + ern);
                float a_ = __expf(e - m0);
                dsel += a_;
                unsigned int v = *(const unsigned int*)(hb + (size_t)s * 128 + lane * 2);
                acc[0] += a_ * bf2f(v & 0xffffu); acc[1] += a_ * bf2f(v >> 16);
            }
            float invd = 1.f / dsel;
            acc[0] *= invd; acc[1] *= invd;
        }
    }
    #pragma unroll
    for (int j = 0; j < EPL; ++j) {
        float o = acc[j] + bias[lane * EPL + j];
        if (RELU) o = fmaxf(o, 0.f);
        out[(size_t)n * HD + lane * EPL + j] = o;
    }
}

// ---------------------------------------------------------------------------

extern "C" void kernel_launch(void* const* d_in, const int* in_sizes, int n_in,
                              void* d_out, int out_size, void* d_ws, size_t ws_size,
                              hipStream_t stream) {
    const float* x   = (const float*)d_in[0];
    const int*   src = (const int*)d_in[1];
    const int*   dst = (const int*)d_in[2];
    const float* W1  = (const float*)d_in[3];
    const float* al1 = (const float*)d_in[4];
    const float* ar1 = (const float*)d_in[5];
    const float* b1  = (const float*)d_in[6];
    const float* W2  = (const float*)d_in[7];
    const float* al2 = (const float*)d_in[8];
    const float* ar2 = (const float*)d_in[9];
    const float* b2  = (const float*)d_in[10];
    float* out = (float*)d_out;

    const int N = in_sizes[0] / 128;  // 50000
    const int E = in_sizes[1];        // 800000

    char* ws = (char*)d_ws;
    size_t oH    = 0;                              // h bf16 [N*256] (L1) / [N*128] (L2, reused)
    size_t oB    = oH + (size_t)N * 256 * 2;       // h1r f32 [N*256]
    size_t oEl1  = oB + (size_t)N * 256 * 4;
    size_t oEr1  = oEl1 + (size_t)N * 4 * 4;
    size_t oEl2  = oEr1 + (size_t)N * 4 * 4;
    size_t oEr2  = oEl2 + (size_t)N * 4;
    size_t oCnt  = oEr2 + (size_t)N * 4;
    size_t oFill = oCnt + (size_t)N * 4;
    size_t oRow  = oFill + (size_t)N * 4;
    size_t oBsum = oRow + (((size_t)(N + 1) * 4 + 15) & ~(size_t)15);
    size_t oBoff = oBsum + 256 * 4;
    size_t oSrcs = oBoff + 256 * 4;

    unsigned short* h1b = (unsigned short*)(ws + oH);
    unsigned short* h2b = (unsigned short*)(ws + oH);  // reuse: h1b dead after agg1
    float* h1r = (float*)(ws + oB);
    float* el1 = (float*)(ws + oEl1);
    float* er1 = (float*)(ws + oEr1);
    float* el2 = (float*)(ws + oEl2);
    float* er2 = (float*)(ws + oEr2);
    int* cnt       = (int*)(ws + oCnt);
    int* fill      = (int*)(ws + oFill);
    int* row_start = (int*)(ws + oRow);
    int* bsum      = (int*)(ws + oBsum);
    int* boff      = (int*)(ws + oBoff);
    int* srcs      = (int*)(ws + oSrcs);

    const int nch = (N + 255) / 256;

    // ---- CSR build (by dst) ----
    hipMemsetAsync(cnt, 0, (size_t)N * 4, stream);
    hist_kernel<<<(E + 255) / 256, 256, 0, stream>>>(dst, cnt, E);
    scan_a_kernel<<<nch, 256, 0, stream>>>(cnt, bsum, N);
    scan_b_kernel<<<1, 256, 0, stream>>>(bsum, boff, nch);
    scan_c_kernel<<<nch, 256, 0, stream>>>(cnt, boff, row_start, N);
    set_end_kernel<<<1, 1, 0, stream>>>(row_start, N, E);
    hipMemsetAsync(fill, 0, (size_t)N * 4, stream);
    scatter_kernel<<<(E + 255) / 256, 256, 0, stream>>>(src, dst, row_start, fill, srcs, E);

    const int ngemmx = (N + 63) / 64;
    const int nwaveb = (N + 3) / 4;

    // ---- layer 1 ----
    gemm_kernel<<<dim3(ngemmx, 4), 256, 0, stream>>>(x, W1, h1b, N, 128, 256);
    dots_h4_kernel<<<nwaveb, 256, 0, stream>>>(h1b, al1, ar1, el1, er1, N);
    agg_kernel<4, 64, true><<<nwaveb, 256, 0, stream>>>(h1b, el1, er1, srcs, row_start, b1, h1r, N);

    // ---- layer 2 ----
    gemm_kernel<<<dim3(ngemmx, 2), 256, 0, stream>>>(h1r, W2, h2b, N, 256, 128);
    dots_h1_kernel<<<nwaveb, 256, 0, stream>>>(h2b, al2, ar2, el2, er2, N);
    agg_kernel<1, 128, false><<<nwaveb, 256, 0, stream>>>(h2b, el2, er2, srcs, row_start, b2, out, N);
}

// Round 5
// 278.532 us; speedup vs baseline: 1.6978x; 1.1769x over previous
//
#include <hip/hip_runtime.h>
#include <hip/hip_bf16.h>
#include <math.h>

// ---------------------------------------------------------------------------
// GAT 2-layer forward, MI355X.
//   CSR build (dst-sorted):  hist -> 2-level scan -> scatter
//   cvt: x->bf16, W1/W2 -> bf16 transposed [M][K]
//   L1: mfma_gemm(xb,W1t)->h1b(bf16) ; dots(h1b)->el1,er1 ; agg->h1rb(bf16,relu)
//   L2: mfma_gemm(h1rb,W2t)->h2b(bf16) ; dots(h2b)->el2,er2 ; agg->d_out(f32)
// R4->R5: GEMMs moved to bf16 MFMA (16x16x32, fp32 accum). K=128/256 fits
// entirely in LDS -> single-stage, one barrier. W pre-transposed so A/B frags
// are contiguous ds_read_b128 (+8-elem row pad -> 2-way alias, free). fp32
// vector GEMMs were ~130us combined (VALU FMA @ ~50TF); MFMA est ~30us.
// agg1 writes bf16 directly (halves its write traffic).
// ---------------------------------------------------------------------------

#define NEG_SLOPE 0.2f

typedef short short8 __attribute__((ext_vector_type(8)));
typedef float float4v __attribute__((ext_vector_type(4)));

static __device__ __forceinline__ float lrelu(float v) {
    return v > 0.f ? v : NEG_SLOPE * v;
}

// bf16 pack/unpack (round-to-nearest-even)
static __device__ __forceinline__ unsigned short f2bf(float f) {
    unsigned int u = __float_as_uint(f);
    u = (u + 0x7fffu + ((u >> 16) & 1u)) >> 16;
    return (unsigned short)u;
}
static __device__ __forceinline__ float bf2f(unsigned int lo16) {
    return __uint_as_float(lo16 << 16);
}

// ---------------------------- CSR build ------------------------------------

__global__ void hist_kernel(const int* __restrict__ dst, int* __restrict__ cnt, int E) {
    int e = blockIdx.x * blockDim.x + threadIdx.x;
    if (e < E) atomicAdd(&cnt[dst[e]], 1);
}

__global__ void scan_a_kernel(const int* __restrict__ cnt, int* __restrict__ bsum, int N) {
    __shared__ int sdata[256];
    int t = threadIdx.x;
    int i = blockIdx.x * 256 + t;
    sdata[t] = (i < N) ? cnt[i] : 0;
    __syncthreads();
    for (int off = 128; off > 0; off >>= 1) {
        if (t < off) sdata[t] += sdata[t + off];
        __syncthreads();
    }
    if (t == 0) bsum[blockIdx.x] = sdata[0];
}

__global__ void scan_b_kernel(const int* __restrict__ bsum, int* __restrict__ boff, int nch) {
    __shared__ int s[256];
    int t = threadIdx.x;
    int v = (t < nch) ? bsum[t] : 0;
    s[t] = v;
    __syncthreads();
    for (int off = 1; off < 256; off <<= 1) {
        int add = (t >= off) ? s[t - off] : 0;
        __syncthreads();
        s[t] += add;
        __syncthreads();
    }
    boff[t] = s[t] - v;  // exclusive
}

__global__ void scan_c_kernel(const int* __restrict__ cnt, const int* __restrict__ boff,
                              int* __restrict__ row_start, int N) {
    __shared__ int s[256];
    int t = threadIdx.x;
    int i = blockIdx.x * 256 + t;
    int v = (i < N) ? cnt[i] : 0;
    s[t] = v;
    __syncthreads();
    for (int off = 1; off < 256; off <<= 1) {
        int add = (t >= off) ? s[t - off] : 0;
        __syncthreads();
        s[t] += add;
        __syncthreads();
    }
    if (i < N) row_start[i] = s[t] - v + boff[blockIdx.x];
}

__global__ void set_end_kernel(int* __restrict__ row_start, int N, int E) {
    row_start[N] = E;
}

__global__ void scatter_kernel(const int* __restrict__ src, const int* __restrict__ dst,
                               const int* __restrict__ row_start, int* __restrict__ fill,
                               int* __restrict__ srcs, int E) {
    int e = blockIdx.x * blockDim.x + threadIdx.x;
    if (e < E) {
        int d = dst[e];
        int pos = row_start[d] + atomicAdd(&fill[d], 1);
        srcs[pos] = src[e];
    }
}

// ---------------------------- dtype converts -------------------------------

// fp32 -> bf16, 8 elems/thread
__global__ void xcvt_kernel(const float* __restrict__ X, unsigned short* __restrict__ Xb,
                            int total8) {
    int idx = blockIdx.x * 256 + threadIdx.x;
    if (idx < total8) {
        float4 a = ((const float4*)X)[idx * 2];
        float4 b = ((const float4*)X)[idx * 2 + 1];
        ushort4 o1, o2;
        o1.x = f2bf(a.x); o1.y = f2bf(a.y); o1.z = f2bf(a.z); o1.w = f2bf(a.w);
        o2.x = f2bf(b.x); o2.y = f2bf(b.y); o2.z = f2bf(b.z); o2.w = f2bf(b.w);
        ((ushort4*)Xb)[idx * 2] = o1;
        ((ushort4*)Xb)[idx * 2 + 1] = o2;
    }
}

// W [K][M] fp32 -> Wt [M][K] bf16 (tiny: 32K elems)
__global__ void wcvt_kernel(const float* __restrict__ W, unsigned short* __restrict__ Wt,
                            int K, int M) {
    int idx = blockIdx.x * 256 + threadIdx.x;
    if (idx < K * M) {
        int k = idx / M, m = idx - k * M;
        Wt[(size_t)m * K + k] = f2bf(W[idx]);
    }
}

// ---------------------------- MFMA GEMM (bf16, fp32 accum) -----------------
// C[N][Mtot](bf16) = A[N][K](bf16) @ Bt[Mtot][K](bf16, pre-transposed W).
// K fits in LDS entirely: one stage, one barrier, no K-tile loop.
// Block: 256 thr = 4 waves; tile 64 rows x MSLICE cols; wave covers MSLICE/4.
// Frag layouts (16x16x32): A row=lane&15,k=(lane>>4)*8+j; B col=lane&15,same k;
// D col=lane&15, row=(lane>>4)*4+j (m89/m91-verified).

template <int K, int MSLICE>
__global__ __launch_bounds__(256) void mfma_gemm_kernel(
        const unsigned short* __restrict__ A,   // [N][K] bf16
        const unsigned short* __restrict__ Bt,  // [Mtot][K] bf16
        unsigned short* __restrict__ C,         // [N][Mtot] bf16
        int N, int Mtot) {
    constexpr int KP = K + 8;        // +16B row pad: 2-way bank alias (free)
    constexpr int CF = MSLICE / 64;  // 16-col frags per wave
    constexpr int KC = K / 8;        // 16B chunks per row
    __shared__ unsigned short As[64 * KP];
    __shared__ unsigned short Bs[MSLICE * KP];
    const int tid = threadIdx.x;
    const int wid = tid >> 6;
    const int lane = tid & 63;
    const int r0 = blockIdx.x * 64;
    const int c0 = blockIdx.y * MSLICE;

    for (int ch = tid; ch < 64 * KC; ch += 256) {
        int row = ch / KC, kc = ch - row * KC;
        int gr = r0 + row;
        short8 v = {};
        if (gr < N) v = *(const short8*)(A + (size_t)gr * K + kc * 8);
        *(short8*)(As + row * KP + kc * 8) = v;
    }
    for (int ch = tid; ch < MSLICE * KC; ch += 256) {
        int row = ch / KC, kc = ch - row * KC;
        *(short8*)(Bs + row * KP + kc * 8) =
            *(const short8*)(Bt + (size_t)(c0 + row) * K + kc * 8);
    }
    __syncthreads();

    float4v acc[4][CF];
    #pragma unroll
    for (int fr = 0; fr < 4; ++fr)
        #pragma unroll
        for (int cf = 0; cf < CF; ++cf)
            acc[fr][cf] = (float4v){0.f, 0.f, 0.f, 0.f};

    const int lr = lane & 15;
    const int lk = (lane >> 4) * 8;
    const int cw = wid * (MSLICE / 4);

    #pragma unroll
    for (int ks = 0; ks < K; ks += 32) {
        short8 af[4], bfr[CF];
        #pragma unroll
        for (int fr = 0; fr < 4; ++fr)
            af[fr] = *(const short8*)(As + (fr * 16 + lr) * KP + ks + lk);
        #pragma unroll
        for (int cf = 0; cf < CF; ++cf)
            bfr[cf] = *(const short8*)(Bs + (cw + cf * 16 + lr) * KP + ks + lk);
        #pragma unroll
        for (int fr = 0; fr < 4; ++fr)
            #pragma unroll
            for (int cf = 0; cf < CF; ++cf)
                acc[fr][cf] = __builtin_amdgcn_mfma_f32_16x16x32_bf16(
                    af[fr], bfr[cf], acc[fr][cf], 0, 0, 0);
    }

    const int rbase = r0 + (lane >> 4) * 4;
    #pragma unroll
    for (int fr = 0; fr < 4; ++fr) {
        #pragma unroll
        for (int cf = 0; cf < CF; ++cf) {
            int col = c0 + cw + cf * 16 + lr;
            #pragma unroll
            for (int j = 0; j < 4; ++j) {
                int row = rbase + fr * 16 + j;
                if (row < N)
                    C[(size_t)row * Mtot + col] = f2bf(acc[fr][cf][j]);
            }
        }
    }
}

// ---------------------------- attention dots -------------------------------

__global__ void dots_h4_kernel(const unsigned short* __restrict__ hb,
                               const float* __restrict__ al, const float* __restrict__ ar,
                               float* __restrict__ el, float* __restrict__ er, int N) {
    int wave = (blockIdx.x * blockDim.x + threadIdx.x) >> 6;
    int lane = threadIdx.x & 63;
    if (wave >= N) return;
    ushort4 hu = *(const ushort4*)(hb + (size_t)wave * 256 + lane * 4);
    float h0 = bf2f(hu.x), h1 = bf2f(hu.y), h2 = bf2f(hu.z), h3 = bf2f(hu.w);
    float4 av = *(const float4*)(al + lane * 4);
    float4 rv = *(const float4*)(ar + lane * 4);
    float pel = h0 * av.x + h1 * av.y + h2 * av.z + h3 * av.w;
    float per = h0 * rv.x + h1 * rv.y + h2 * rv.z + h3 * rv.w;
    #pragma unroll
    for (int mask = 1; mask < 16; mask <<= 1) {
        pel += __shfl_xor(pel, mask);
        per += __shfl_xor(per, mask);
    }
    if ((lane & 15) == 0) {
        el[(size_t)wave * 4 + (lane >> 4)] = pel;
        er[(size_t)wave * 4 + (lane >> 4)] = per;
    }
}

__global__ void dots_h1_kernel(const unsigned short* __restrict__ hb,
                               const float* __restrict__ al, const float* __restrict__ ar,
                               float* __restrict__ el, float* __restrict__ er, int N) {
    int wave = (blockIdx.x * blockDim.x + threadIdx.x) >> 6;
    int lane = threadIdx.x & 63;
    if (wave >= N) return;
    unsigned int hu = *(const unsigned int*)(hb + (size_t)wave * 128 + lane * 2);
    float h0 = bf2f(hu & 0xffffu), h1 = bf2f(hu >> 16);
    float2 av = *(const float2*)(al + lane * 2);
    float2 rv = *(const float2*)(ar + lane * 2);
    float pel = h0 * av.x + h1 * av.y;
    float per = h0 * rv.x + h1 * rv.y;
    #pragma unroll
    for (int mask = 1; mask < 64; mask <<= 1) {
        pel += __shfl_xor(pel, mask);
        per += __shfl_xor(per, mask);
    }
    if (lane == 0) {
        el[wave] = pel;
        er[wave] = per;
    }
}

// ---------------------------- edge softmax + aggregation -------------------
// One wave per dst node. Edge list + alpha staged in registers (striped),
// pass2 pulls s_i / a_i via __shfl and gathers bf16 h rows, fp32 accumulate.
// OT = unsigned short (bf16 out) or float.

template <int H, int D, bool RELU, typename OT>
__global__ __launch_bounds__(256) void agg_kernel(const unsigned short* __restrict__ hb,
                           const float* __restrict__ el, const float* __restrict__ er,
                           const int* __restrict__ srcs, const int* __restrict__ row_start,
                           const float* __restrict__ bias, OT* __restrict__ out, int N) {
    constexpr int HD = H * D;
    constexpr int EPL = HD / 64;  // elems per lane (4 for L1, 2 for L2)
    int wave = (blockIdx.x * blockDim.x + threadIdx.x) >> 6;
    int lane = threadIdx.x & 63;
    if (wave >= N) return;
    const int n = wave;
    const int rs = row_start[n];
    const int re = row_start[n + 1];
    const int deg = re - rs;

    float acc[EPL];
    #pragma unroll
    for (int j = 0; j < EPL; ++j) acc[j] = 0.f;

    if (deg > 0) {
        const int cnt0 = deg < 64 ? deg : 64;

        if constexpr (H == 4) {
            const int h = lane >> 4;  // 0..3
            const bool hhi = (h >= 2), hodd = (h & 1);
            const float4 ern = *(const float4*)(er + (size_t)n * 4);
            int sv = 0;
            float e0 = -INFINITY, e1 = -INFINITY, e2 = -INFINITY, e3 = -INFINITY;
            if (lane < cnt0) {
                sv = srcs[rs + lane];
                float4 ev = *(const float4*)(el + (size_t)sv * 4);
                e0 = lrelu(ev.x + ern.x);
                e1 = lrelu(ev.y + ern.y);
                e2 = lrelu(ev.z + ern.z);
                e3 = lrelu(ev.w + ern.w);
            }
            float m0 = e0, m1 = e1, m2 = e2, m3 = e3;
            for (int base = rs + 64; base < re; base += 64) {  // rare
                int idx = base + lane;
                if (idx < re) {
                    int s = srcs[idx];
                    float4 ev = *(const float4*)(el + (size_t)s * 4);
                    m0 = fmaxf(m0, lrelu(ev.x + ern.x));
                    m1 = fmaxf(m1, lrelu(ev.y + ern.y));
                    m2 = fmaxf(m2, lrelu(ev.z + ern.z));
                    m3 = fmaxf(m3, lrelu(ev.w + ern.w));
                }
            }
            #pragma unroll
            for (int mask = 1; mask < 64; mask <<= 1) {
                m0 = fmaxf(m0, __shfl_xor(m0, mask));
                m1 = fmaxf(m1, __shfl_xor(m1, mask));
                m2 = fmaxf(m2, __shfl_xor(m2, mask));
                m3 = fmaxf(m3, __shfl_xor(m3, mask));
            }
            float a0 = __expf(e0 - m0), a1 = __expf(e1 - m1);
            float a2 = __expf(e2 - m2), a3 = __expf(e3 - m3);
            float d0 = a0, d1 = a1, d2 = a2, d3 = a3;
            #pragma unroll
            for (int mask = 1; mask < 64; mask <<= 1) {
                d0 += __shfl_xor(d0, mask);
                d1 += __shfl_xor(d1, mask);
                d2 += __shfl_xor(d2, mask);
                d3 += __shfl_xor(d3, mask);
            }
            float dsel  = hhi ? (hodd ? d3 : d2) : (hodd ? d1 : d0);
            const float msel  = hhi ? (hodd ? m3 : m2) : (hodd ? m1 : m0);
            const float ersel = hhi ? (hodd ? ern.w : ern.z) : (hodd ? ern.y : ern.x);
            int i = 0;
            for (; i + 4 <= cnt0; i += 4) {
                int s0 = __shfl(sv, i), s1 = __shfl(sv, i + 1);
                int s2 = __shfl(sv, i + 2), s3 = __shfl(sv, i + 3);
                float t00 = __shfl(a0, i), t01 = __shfl(a1, i), t02 = __shfl(a2, i), t03 = __shfl(a3, i);
                float t10 = __shfl(a0, i + 1), t11 = __shfl(a1, i + 1), t12 = __shfl(a2, i + 1), t13 = __shfl(a3, i + 1);
                float t20 = __shfl(a0, i + 2), t21 = __shfl(a1, i + 2), t22 = __shfl(a2, i + 2), t23 = __shfl(a3, i + 2);
                float t30 = __shfl(a0, i + 3), t31 = __shfl(a1, i + 3), t32 = __shfl(a2, i + 3), t33 = __shfl(a3, i + 3);
                float w0 = hhi ? (hodd ? t03 : t02) : (hodd ? t01 : t00);
                float w1 = hhi ? (hodd ? t13 : t12) : (hodd ? t11 : t10);
                float w2 = hhi ? (hodd ? t23 : t22) : (hodd ? t21 : t20);
                float w3 = hhi ? (hodd ? t33 : t32) : (hodd ? t31 : t30);
                uint2 v0 = *(const uint2*)(hb + (size_t)s0 * 256 + lane * 4);
                uint2 v1 = *(const uint2*)(hb + (size_t)s1 * 256 + lane * 4);
                uint2 v2 = *(const uint2*)(hb + (size_t)s2 * 256 + lane * 4);
                uint2 v3 = *(const uint2*)(hb + (size_t)s3 * 256 + lane * 4);
                acc[0] += w0 * bf2f(v0.x & 0xffffu); acc[1] += w0 * bf2f(v0.x >> 16);
                acc[2] += w0 * bf2f(v0.y & 0xffffu); acc[3] += w0 * bf2f(v0.y >> 16);
                acc[0] += w1 * bf2f(v1.x & 0xffffu); acc[1] += w1 * bf2f(v1.x >> 16);
                acc[2] += w1 * bf2f(v1.y & 0xffffu); acc[3] += w1 * bf2f(v1.y >> 16);
                acc[0] += w2 * bf2f(v2.x & 0xffffu); acc[1] += w2 * bf2f(v2.x >> 16);
                acc[2] += w2 * bf2f(v2.y & 0xffffu); acc[3] += w2 * bf2f(v2.y >> 16);
                acc[0] += w3 * bf2f(v3.x & 0xffffu); acc[1] += w3 * bf2f(v3.x >> 16);
                acc[2] += w3 * bf2f(v3.y & 0xffffu); acc[3] += w3 * bf2f(v3.y >> 16);
            }
            for (; i < cnt0; ++i) {
                int s0 = __shfl(sv, i);
                float t0 = __shfl(a0, i), t1 = __shfl(a1, i), t2 = __shfl(a2, i), t3 = __shfl(a3, i);
                float w = hhi ? (hodd ? t3 : t2) : (hodd ? t1 : t0);
                uint2 v = *(const uint2*)(hb + (size_t)s0 * 256 + lane * 4);
                acc[0] += w * bf2f(v.x & 0xffffu); acc[1] += w * bf2f(v.x >> 16);
                acc[2] += w * bf2f(v.y & 0xffffu); acc[3] += w * bf2f(v.y >> 16);
            }
            for (int idx = rs + 64; idx < re; ++idx) {  // rare
                int s = srcs[idx];
                float e = lrelu(el[(size_t)s * 4 + h] + ersel);
                float a_ = __expf(e - msel);
                dsel += a_;
                uint2 v = *(const uint2*)(hb + (size_t)s * 256 + lane * 4);
                acc[0] += a_ * bf2f(v.x & 0xffffu); acc[1] += a_ * bf2f(v.x >> 16);
                acc[2] += a_ * bf2f(v.y & 0xffffu); acc[3] += a_ * bf2f(v.y >> 16);
            }
            float invd = 1.f / dsel;
            #pragma unroll
            for (int j = 0; j < 4; ++j) acc[j] *= invd;
        } else {  // H == 1, D = 128, EPL = 2
            const float ern = er[n];
            int sv = 0;
            float e0 = -INFINITY;
            if (lane < cnt0) {
                sv = srcs[rs + lane];
                e0 = lrelu(el[sv] + ern);
            }
            float m0 = e0;
            for (int base = rs + 64; base < re; base += 64) {  // rare
                int idx = base + lane;
                if (idx < re) m0 = fmaxf(m0, lrelu(el[srcs[idx]] + ern));
            }
            #pragma unroll
            for (int mask = 1; mask < 64; mask <<= 1)
                m0 = fmaxf(m0, __shfl_xor(m0, mask));
            float a0 = __expf(e0 - m0);
            float d0 = a0;
            #pragma unroll
            for (int mask = 1; mask < 64; mask <<= 1)
                d0 += __shfl_xor(d0, mask);
            float dsel = d0;
            int i = 0;
            for (; i + 4 <= cnt0; i += 4) {
                int s0 = __shfl(sv, i), s1 = __shfl(sv, i + 1);
                int s2 = __shfl(sv, i + 2), s3 = __shfl(sv, i + 3);
                float w0 = __shfl(a0, i), w1 = __shfl(a0, i + 1);
                float w2 = __shfl(a0, i + 2), w3 = __shfl(a0, i + 3);
                unsigned int v0 = *(const unsigned int*)(hb + (size_t)s0 * 128 + lane * 2);
                unsigned int v1 = *(const unsigned int*)(hb + (size_t)s1 * 128 + lane * 2);
                unsigned int v2 = *(const unsigned int*)(hb + (size_t)s2 * 128 + lane * 2);
                unsigned int v3 = *(const unsigned int*)(hb + (size_t)s3 * 128 + lane * 2);
                acc[0] += w0 * bf2f(v0 & 0xffffu); acc[1] += w0 * bf2f(v0 >> 16);
                acc[0] += w1 * bf2f(v1 & 0xffffu); acc[1] += w1 * bf2f(v1 >> 16);
                acc[0] += w2 * bf2f(v2 & 0xffffu); acc[1] += w2 * bf2f(v2 >> 16);
                acc[0] += w3 * bf2f(v3 & 0xffffu); acc[1] += w3 * bf2f(v3 >> 16);
            }
            for (; i < cnt0; ++i) {
                int s0 = __shfl(sv, i);
                float w = __shfl(a0, i);
                unsigned int v = *(const unsigned int*)(hb + (size_t)s0 * 128 + lane * 2);
                acc[0] += w * bf2f(v & 0xffffu); acc[1] += w * bf2f(v >> 16);
            }
            for (int idx = rs + 64; idx < re; ++idx) {  // rare
                int s = srcs[idx];
                float e = lrelu(el[s] + ern);
                float a_ = __expf(e - m0);
                dsel += a_;
                unsigned int v = *(const unsigned int*)(hb + (size_t)s * 128 + lane * 2);
                acc[0] += a_ * bf2f(v & 0xffffu); acc[1] += a_ * bf2f(v >> 16);
            }
            float invd = 1.f / dsel;
            acc[0] *= invd; acc[1] *= invd;
        }
    }
    #pragma unroll
    for (int j = 0; j < EPL; ++j) {
        float o = acc[j] + bias[lane * EPL + j];
        if (RELU) o = fmaxf(o, 0.f);
        if constexpr (sizeof(OT) == 2)
            out[(size_t)n * HD + lane * EPL + j] = f2bf(o);
        else
            out[(size_t)n * HD + lane * EPL + j] = o;
    }
}

// ---------------------------------------------------------------------------

extern "C" void kernel_launch(void* const* d_in, const int* in_sizes, int n_in,
                              void* d_out, int out_size, void* d_ws, size_t ws_size,
                              hipStream_t stream) {
    const float* x   = (const float*)d_in[0];
    const int*   src = (const int*)d_in[1];
    const int*   dst = (const int*)d_in[2];
    const float* W1  = (const float*)d_in[3];
    const float* al1 = (const float*)d_in[4];
    const float* ar1 = (const float*)d_in[5];
    const float* b1  = (const float*)d_in[6];
    const float* W2  = (const float*)d_in[7];
    const float* al2 = (const float*)d_in[8];
    const float* ar2 = (const float*)d_in[9];
    const float* b2  = (const float*)d_in[10];
    float* out = (float*)d_out;

    const int N = in_sizes[0] / 128;  // 50000
    const int E = in_sizes[1];        // 800000

    char* ws = (char*)d_ws;
    size_t oXB   = 0;                              // xb bf16 [N*128]
    size_t oH    = oXB + (size_t)N * 128 * 2;      // h1b/h2b bf16 [N*256]
    size_t oB    = oH + (size_t)N * 256 * 2;       // h1rb bf16 [N*256]
    size_t oW1t  = oB + (size_t)N * 256 * 2;       // W1t bf16 [256*128]
    size_t oW2t  = oW1t + 256 * 128 * 2;           // W2t bf16 [128*256]
    size_t oEl1  = oW2t + 128 * 256 * 2;
    size_t oEr1  = oEl1 + (size_t)N * 4 * 4;
    size_t oEl2  = oEr1 + (size_t)N * 4 * 4;
    size_t oEr2  = oEl2 + (size_t)N * 4;
    size_t oCnt  = oEr2 + (size_t)N * 4;
    size_t oFill = oCnt + (size_t)N * 4;
    size_t oRow  = oFill + (size_t)N * 4;
    size_t oBsum = oRow + (((size_t)(N + 1) * 4 + 15) & ~(size_t)15);
    size_t oBoff = oBsum + 256 * 4;
    size_t oSrcs = oBoff + 256 * 4;

    unsigned short* xb   = (unsigned short*)(ws + oXB);
    unsigned short* h1b  = (unsigned short*)(ws + oH);
    unsigned short* h2b  = (unsigned short*)(ws + oH);  // reuse: h1b dead after agg1
    unsigned short* h1rb = (unsigned short*)(ws + oB);
    unsigned short* w1t  = (unsigned short*)(ws + oW1t);
    unsigned short* w2t  = (unsigned short*)(ws + oW2t);
    float* el1 = (float*)(ws + oEl1);
    float* er1 = (float*)(ws + oEr1);
    float* el2 = (float*)(ws + oEl2);
    float* er2 = (float*)(ws + oEr2);
    int* cnt       = (int*)(ws + oCnt);
    int* fill      = (int*)(ws + oFill);
    int* row_start = (int*)(ws + oRow);
    int* bsum      = (int*)(ws + oBsum);
    int* boff      = (int*)(ws + oBoff);
    int* srcs      = (int*)(ws + oSrcs);

    const int nch = (N + 255) / 256;

    // ---- CSR build (by dst) ----
    hipMemsetAsync(cnt, 0, (size_t)N * 4, stream);
    hist_kernel<<<(E + 255) / 256, 256, 0, stream>>>(dst, cnt, E);
    scan_a_kernel<<<nch, 256, 0, stream>>>(cnt, bsum, N);
    scan_b_kernel<<<1, 256, 0, stream>>>(bsum, boff, nch);
    scan_c_kernel<<<nch, 256, 0, stream>>>(cnt, boff, row_start, N);
    set_end_kernel<<<1, 1, 0, stream>>>(row_start, N, E);
    hipMemsetAsync(fill, 0, (size_t)N * 4, stream);
    scatter_kernel<<<(E + 255) / 256, 256, 0, stream>>>(src, dst, row_start, fill, srcs, E);

    // ---- converts ----
    const int x8 = N * 128 / 8;
    xcvt_kernel<<<(x8 + 255) / 256, 256, 0, stream>>>(x, xb, x8);
    wcvt_kernel<<<(128 * 256 + 255) / 256, 256, 0, stream>>>(W1, w1t, 128, 256);
    wcvt_kernel<<<(256 * 128 + 255) / 256, 256, 0, stream>>>(W2, w2t, 256, 128);

    const int nrowb = (N + 63) / 64;   // 782
    const int nwaveb = (N + 3) / 4;

    // ---- layer 1 ----
    mfma_gemm_kernel<128, 128><<<dim3(nrowb, 2), 256, 0, stream>>>(xb, w1t, h1b, N, 256);
    dots_h4_kernel<<<nwaveb, 256, 0, stream>>>(h1b, al1, ar1, el1, er1, N);
    agg_kernel<4, 64, true, unsigned short><<<nwaveb, 256, 0, stream>>>(
        h1b, el1, er1, srcs, row_start, b1, h1rb, N);

    // ---- layer 2 ----
    mfma_gemm_kernel<256, 64><<<dim3(nrowb, 2), 256, 0, stream>>>(h1rb, w2t, h2b, N, 128);
    dots_h1_kernel<<<nwaveb, 256, 0, stream>>>(h2b, al2, ar2, el2, er2, N);
    agg_kernel<1, 128, false, float><<<nwaveb, 256, 0, stream>>>(
        h2b, el2, er2, srcs, row_start, b2, out, N);
}